// Round 2
// baseline (430.490 us; speedup 1.0000x reference)
//
#include <hip/hip_runtime.h>

// LookupAttention: B=1,H=12,N=2048,D=64, T=8, S=256, C=8, KQ=KV=4
#define HH   12
#define NN   2048
#define DD   64
#define TT   8
#define SS   256
#define KK   4

// ---------------- Kernel 1: selection (both sides) ----------------
// Grid: 2 sides * 12 h * 64 tiles = 1536 blocks, 256 threads (4 waves).
// Block handles 32 rows of one (side,h). Wave handles 8 rows; lane = (r,t):
// each lane does the FULL per-(n,t) selection serially (no cross-lane ops).
__global__ __launch_bounds__(256) void select_topk(
    const float* __restrict__ q, const float* __restrict__ kx,
    const float* __restrict__ proj,
    float* __restrict__ selw, unsigned* __restrict__ selidx) {
  __shared__ float pj[64 * 68];  // row = c*8+t, stride 68 (16B-aligned, banks 4t -> conflict-free)
  __shared__ float xr[32 * 72];  // row stride 72 (16B-aligned, 2-way broadcast ok)

  int b = blockIdx.x;
  int side = b / 768;
  int rem  = b - side * 768;
  int h    = rem >> 6;
  int n0   = (rem & 63) * 32;
  const float* src = side ? kx : q;

  // stage proj[h] (4096 floats), transposed rows (c*8+t)
  for (int e = threadIdx.x; e < 4096; e += 256) {
    int t = e >> 9, c = (e >> 6) & 7, d = e & 63;
    pj[(c * 8 + t) * 68 + d] = proj[h * 4096 + e];
  }
  // stage 32 x-rows
  for (int e = threadIdx.x; e < 2048; e += 256) {
    int r = e >> 6, d = e & 63;
    xr[r * 72 + d] = src[((size_t)h * NN + n0 + r) * DD + d];
  }
  __syncthreads();

  int wave = threadIdx.x >> 6, lane = threadIdx.x & 63;
  int r = lane >> 3, t = lane & 7;
  int row = wave * 8 + r;
  int n = n0 + row;

  // 8 dot products s[c] = x . proj[h][t][c]
  float s[8] = {0.f,0.f,0.f,0.f,0.f,0.f,0.f,0.f};
  const float* xrow = &xr[row * 72];
  for (int d0 = 0; d0 < 64; d0 += 4) {
    float4 xv = *(const float4*)(xrow + d0);
#pragma unroll
    for (int c = 0; c < 8; ++c) {
      float4 pv = *(const float4*)(&pj[(c * 8 + t) * 68 + d0]);
      s[c] += xv.x * pv.x; s[c] += xv.y * pv.y;
      s[c] += xv.z * pv.z; s[c] += xv.w * pv.w;
    }
  }
  float p[8];
#pragma unroll
  for (int c = 0; c < 8; ++c) p[c] = 1.0f / (1.0f + expf(-s[c]));

  // exact reference doubling over bits 0..5 -> w[64] (static-indexed registers)
  float w[64];
  w[0] = 1.0f - p[0]; w[1] = p[0];
#pragma unroll
  for (int c = 1; c <= 5; ++c) {
    int L = 1 << c;
    float pc = p[c], qc = 1.0f - p[c];
#pragma unroll 32
    for (int j = 0; j < 32; ++j) {   // static bound; guard inside
      if (j < L) { w[j + L] = w[j] * pc; w[j] = w[j] * qc; }
    }
  }
  float f6[2] = {1.0f - p[6], p[6]};
  float f7[2] = {1.0f - p[7], p[7]};

  // exact top-4 scan, ascending bucket index, strict > (JAX tie rule)
  float m0 = -1.f, m1 = -1.f, m2 = -1.f, m3 = -1.f;
  int   i0 = 0, i1 = 0, i2 = 0, i3 = 0;
  for (int hi = 0; hi < 4; ++hi) {     // hi = b7*2+b6; bucket = b7*128+b6*64+j
    int b7 = hi >> 1, b6 = hi & 1;
    float fa = f6[b6], fb = f7[b7];
    int base = b7 * 128 + b6 * 64;
#pragma unroll 64
    for (int j = 0; j < 64; ++j) {
      float v = (w[j] * fa) * fb;
      int idx = base + j;
      bool c0 = v > m0, c1 = v > m1, c2 = v > m2, c3 = v > m3;
      m3 = c2 ? m2 : (c3 ? v : m3);  i3 = c2 ? i2 : (c3 ? idx : i3);
      m2 = c1 ? m1 : (c2 ? v : m2);  i2 = c1 ? i1 : (c2 ? idx : i2);
      m1 = c0 ? m0 : (c1 ? v : m1);  i1 = c0 ? i0 : (c1 ? idx : i1);
      m0 = c0 ? v : m0;              i0 = c0 ? idx : i0;
    }
  }

  size_t o = (((size_t)side * HH + h) * TT + t) * NN + n;
  ((float4*)selw)[o] = make_float4(m0, m1, m2, m3);
  selidx[o] = (unsigned)i0 | ((unsigned)i1 << 8) | ((unsigned)i2 << 16) | ((unsigned)i3 << 24);
}

// ---------------- Kernel 2: build tables (LDS-resident) ----------------
// Grid: 12*8*2 = 192 blocks, 256 threads. Block = (h,t,g): g = half of n-range.
__global__ __launch_bounds__(256) void build_tables(
    const float* __restrict__ v, const float* __restrict__ mask,
    const float* __restrict__ selw, const unsigned* __restrict__ selidx,
    float* __restrict__ tables) {
  __shared__ float tbl[SS * DD];  // 64KB
  int b = blockIdx.x;
  int g = b & 1;
  int ht = b >> 1;           // h*8+t
  int h = ht >> 3;

  for (int e = threadIdx.x; e < SS * DD; e += 256) tbl[e] = 0.0f;
  __syncthreads();

  int wave = threadIdx.x >> 6, lane = threadIdx.x & 63;
  int nend = (g + 1) * 1024;
  for (int n = g * 1024 + wave; n < nend; n += 4) {
    size_t o = ((size_t)ht) * NN + n;            // side 0 (q)
    float4 w4 = ((const float4*)selw)[o];
    unsigned ip = selidx[o];
    float vd = v[((size_t)h * NN + n) * DD + lane] * mask[n];
    atomicAdd(&tbl[(ip & 255u) * DD + lane],         w4.x * vd);
    atomicAdd(&tbl[((ip >> 8) & 255u) * DD + lane],  w4.y * vd);
    atomicAdd(&tbl[((ip >> 16) & 255u) * DD + lane], w4.z * vd);
    atomicAdd(&tbl[(ip >> 24) * DD + lane],          w4.w * vd);
  }
  __syncthreads();
  float* gt = tables + (size_t)ht * SS * DD;
  for (int e = threadIdx.x; e < SS * DD; e += 256) atomicAdd(&gt[e], tbl[e]);
}

// ---------------- Kernel 3: gather ----------------
// Grid: 24576 waves / 4 = 6144 blocks, 256 threads. Wave per (h,n), lane = d.
__global__ __launch_bounds__(256) void gather_out(
    const float* __restrict__ selw, const unsigned* __restrict__ selidx,
    const float* __restrict__ tables, float* __restrict__ out) {
  int wid = blockIdx.x * 4 + (threadIdx.x >> 6);
  int lane = threadIdx.x & 63;
  int h = wid >> 11;
  int n = wid & 2047;

  float acc = 0.0f;
#pragma unroll
  for (int t = 0; t < TT; ++t) {
    size_t o = (((size_t)HH + h) * TT + t) * NN + n;   // side 1 (k): (1*HH+h)
    float4 w4 = ((const float4*)selw)[o];
    unsigned ip = selidx[o];
    const float* tb = tables + ((size_t)h * TT + t) * SS * DD;
    acc += w4.x * tb[(ip & 255u) * DD + lane];
    acc += w4.y * tb[((ip >> 8) & 255u) * DD + lane];
    acc += w4.z * tb[((ip >> 16) & 255u) * DD + lane];
    acc += w4.w * tb[(ip >> 24) * DD + lane];
  }
  out[((size_t)h * NN + n) * DD + lane] = acc * 0.125f;
}

extern "C" void kernel_launch(void* const* d_in, const int* in_sizes, int n_in,
                              void* d_out, int out_size, void* d_ws, size_t ws_size,
                              hipStream_t stream) {
  const float* q    = (const float*)d_in[0];
  const float* k    = (const float*)d_in[1];
  const float* v    = (const float*)d_in[2];
  const float* mask = (const float*)d_in[3];
  const float* proj = (const float*)d_in[4];
  float* out = (float*)d_out;

  float*    tables = (float*)d_ws;                       // 1,572,864 f32 = 6.29MB
  float*    selw   = tables + (size_t)HH * TT * SS * DD; // 1,572,864 f32 = 6.29MB
  unsigned* selidx = (unsigned*)(selw + (size_t)2 * HH * TT * NN * KK); // 393,216 u32

  hipMemsetAsync(tables, 0, (size_t)HH * TT * SS * DD * sizeof(float), stream);

  select_topk<<<dim3(1536), dim3(256), 0, stream>>>(q, k, proj, selw, selidx);
  build_tables<<<dim3(192), dim3(256), 0, stream>>>(v, mask, selw, selidx, tables);
  gather_out<<<dim3(6144), dim3(256), 0, stream>>>(selw, selidx, tables, out);
}

// Round 3
// 145.790 us; speedup vs baseline: 2.9528x; 2.9528x over previous
//
#include <hip/hip_runtime.h>

// LookupAttention: B=1,H=12,N=2048,D=64, T=8, S=256, C=8, KQ=KV=4
#define HH   12
#define NN   2048
#define DD   64
#define TT   8
#define SS   256
#define KK   4
#define NHT  (HH * TT)   // 96

// ---------------- Kernel 1: selection (both sides) + side-0 bucket counts ----
// Grid: 2 sides * 12 h * 64 tiles = 1536 blocks, 256 threads (4 waves).
// Wave handles 8 rows; lane = (r,t): full per-(n,t) selection serially in-lane.
__global__ __launch_bounds__(256) void select_topk(
    const float* __restrict__ q, const float* __restrict__ kx,
    const float* __restrict__ proj,
    float* __restrict__ selw, unsigned* __restrict__ selidx,
    unsigned* __restrict__ counts) {
  __shared__ float pj[64 * 68];  // row = c*8+t, stride 68
  __shared__ float xr[32 * 72];  // row stride 72

  int b = blockIdx.x;
  int side = b / 768;
  int rem  = b - side * 768;
  int h    = rem >> 6;
  int n0   = (rem & 63) * 32;
  const float* src = side ? kx : q;

  for (int e = threadIdx.x; e < 4096; e += 256) {
    int t = e >> 9, c = (e >> 6) & 7, d = e & 63;
    pj[(c * 8 + t) * 68 + d] = proj[h * 4096 + e];
  }
  for (int e = threadIdx.x; e < 2048; e += 256) {
    int r = e >> 6, d = e & 63;
    xr[r * 72 + d] = src[((size_t)h * NN + n0 + r) * DD + d];
  }
  __syncthreads();

  int wave = threadIdx.x >> 6, lane = threadIdx.x & 63;
  int r = lane >> 3, t = lane & 7;
  int row = wave * 8 + r;
  int n = n0 + row;

  float s[8] = {0.f,0.f,0.f,0.f,0.f,0.f,0.f,0.f};
  const float* xrow = &xr[row * 72];
  for (int d0 = 0; d0 < 64; d0 += 4) {
    float4 xv = *(const float4*)(xrow + d0);
#pragma unroll
    for (int c = 0; c < 8; ++c) {
      float4 pv = *(const float4*)(&pj[(c * 8 + t) * 68 + d0]);
      s[c] += xv.x * pv.x; s[c] += xv.y * pv.y;
      s[c] += xv.z * pv.z; s[c] += xv.w * pv.w;
    }
  }
  float p[8];
#pragma unroll
  for (int c = 0; c < 8; ++c) p[c] = 1.0f / (1.0f + expf(-s[c]));

  // exact reference doubling over bits 0..5 -> w[64] (static-indexed)
  float w[64];
  w[0] = 1.0f - p[0]; w[1] = p[0];
#pragma unroll
  for (int c = 1; c <= 5; ++c) {
    int L = 1 << c;
    float pc = p[c], qc = 1.0f - p[c];
#pragma unroll 32
    for (int j = 0; j < 32; ++j) {
      if (j < L) { w[j + L] = w[j] * pc; w[j] = w[j] * qc; }
    }
  }
  float f6[2] = {1.0f - p[6], p[6]};
  float f7[2] = {1.0f - p[7], p[7]};

  // exact top-4 scan, ascending bucket index, strict > (JAX tie rule)
  float m0 = -1.f, m1 = -1.f, m2 = -1.f, m3 = -1.f;
  int   i0 = 0, i1 = 0, i2 = 0, i3 = 0;
  for (int hi = 0; hi < 4; ++hi) {
    int b7 = hi >> 1, b6 = hi & 1;
    float fa = f6[b6], fb = f7[b7];
    int base = b7 * 128 + b6 * 64;
#pragma unroll 64
    for (int j = 0; j < 64; ++j) {
      float v = (w[j] * fa) * fb;
      int idx = base + j;
      bool c0 = v > m0, c1 = v > m1, c2 = v > m2, c3 = v > m3;
      m3 = c2 ? m2 : (c3 ? v : m3);  i3 = c2 ? i2 : (c3 ? idx : i3);
      m2 = c1 ? m1 : (c2 ? v : m2);  i2 = c1 ? i1 : (c2 ? idx : i2);
      m1 = c0 ? m0 : (c1 ? v : m1);  i1 = c0 ? i0 : (c1 ? idx : i1);
      m0 = c0 ? v : m0;              i0 = c0 ? idx : i0;
    }
  }

  int ht = h * TT + t;
  size_t o = ((size_t)side * NHT + ht) * NN + n;
  ((float4*)selw)[o] = make_float4(m0, m1, m2, m3);
  selidx[o] = (unsigned)i0 | ((unsigned)i1 << 8) | ((unsigned)i2 << 16) | ((unsigned)i3 << 24);

  if (side == 0) {  // bucket histogram for the q-side scatter bins
    unsigned* cb = counts + (size_t)ht * SS;
    atomicAdd(&cb[i0], 1u); atomicAdd(&cb[i1], 1u);
    atomicAdd(&cb[i2], 1u); atomicAdd(&cb[i3], 1u);
  }
}

// ---------------- Kernel 2: per-(h,t) scan + scatter entries into bins -------
// Grid: 96 blocks, 256 threads. Entry = u64 { hi: bits(w*mask), lo: n }.
__global__ __launch_bounds__(256) void scan_scatter(
    const float* __restrict__ selw, const unsigned* __restrict__ selidx,
    const float* __restrict__ mask, const unsigned* __restrict__ counts,
    unsigned* __restrict__ offsets, unsigned long long* __restrict__ entries) {
  __shared__ unsigned offs[SS];
  __shared__ unsigned cur[SS];
  int ht = blockIdx.x;
  int tid = threadIdx.x;

  if (tid < 64) {  // wave 0: exclusive scan of 256 counts (4 per lane)
    int lane = tid;
    const unsigned* cb = counts + (size_t)ht * SS;
    unsigned c0 = cb[lane*4], c1 = cb[lane*4+1], c2 = cb[lane*4+2], c3 = cb[lane*4+3];
    unsigned sum = c0 + c1 + c2 + c3;
    unsigned x = sum;
#pragma unroll
    for (int off = 1; off <= 32; off <<= 1) {
      unsigned y = __shfl_up(x, off);
      if (lane >= off) x += y;
    }
    unsigned excl = x - sum;
    unsigned o0 = excl, o1 = excl + c0, o2 = o1 + c1, o3 = o2 + c2;
    offs[lane*4] = o0; offs[lane*4+1] = o1; offs[lane*4+2] = o2; offs[lane*4+3] = o3;
    cur [lane*4] = o0; cur [lane*4+1] = o1; cur [lane*4+2] = o2; cur [lane*4+3] = o3;
    unsigned* ob = offsets + (size_t)ht * SS;
    ob[lane*4] = o0; ob[lane*4+1] = o1; ob[lane*4+2] = o2; ob[lane*4+3] = o3;
  }
  __syncthreads();

  unsigned long long* eb = entries + (size_t)ht * (NN * KK);
  for (int n = tid; n < NN; n += 256) {
    size_t o = (size_t)ht * NN + n;   // side 0 region
    float4 w4 = ((const float4*)selw)[o];
    unsigned ip = selidx[o];
    float m = mask[n];
    unsigned b0 = ip & 255u, b1 = (ip >> 8) & 255u, b2 = (ip >> 16) & 255u, b3 = ip >> 24;
    unsigned s0 = atomicAdd(&cur[b0], 1u);
    eb[s0] = ((unsigned long long)__float_as_uint(w4.x * m) << 32) | (unsigned)n;
    unsigned s1 = atomicAdd(&cur[b1], 1u);
    eb[s1] = ((unsigned long long)__float_as_uint(w4.y * m) << 32) | (unsigned)n;
    unsigned s2 = atomicAdd(&cur[b2], 1u);
    eb[s2] = ((unsigned long long)__float_as_uint(w4.z * m) << 32) | (unsigned)n;
    unsigned s3 = atomicAdd(&cur[b3], 1u);
    eb[s3] = ((unsigned long long)__float_as_uint(w4.w * m) << 32) | (unsigned)n;
  }
}

// ---------------- Kernel 3: build tables by gathering bins -------------------
// Grid: 24576 waves / 4 = 6144 blocks. Wave = (ht, s); lane = d. No atomics.
__global__ __launch_bounds__(256) void build_tables(
    const float* __restrict__ v, const unsigned* __restrict__ counts,
    const unsigned* __restrict__ offsets,
    const unsigned long long* __restrict__ entries,
    float* __restrict__ tables) {
  int wid = blockIdx.x * 4 + (threadIdx.x >> 6);
  int lane = threadIdx.x & 63;
  int ht = wid >> 8;
  int s  = wid & 255;
  int h  = ht >> 3;

  unsigned beg = offsets[(size_t)ht * SS + s];
  unsigned cnt = counts [(size_t)ht * SS + s];
  const unsigned long long* e = entries + (size_t)ht * (NN * KK) + beg;
  const float* vh = v + (size_t)h * NN * DD;

  float acc = 0.0f;
  unsigned i = 0;
  for (; i + 2 <= cnt; i += 2) {
    unsigned long long e0 = e[i], e1 = e[i + 1];
    unsigned n0 = (unsigned)e0, n1 = (unsigned)e1;
    float w0 = __uint_as_float((unsigned)(e0 >> 32));
    float w1 = __uint_as_float((unsigned)(e1 >> 32));
    acc += w0 * vh[(size_t)n0 * DD + lane];
    acc += w1 * vh[(size_t)n1 * DD + lane];
  }
  if (i < cnt) {
    unsigned long long e0 = e[i];
    acc += __uint_as_float((unsigned)(e0 >> 32)) * vh[(size_t)(unsigned)e0 * DD + lane];
  }
  tables[(size_t)wid * DD + lane] = acc;
}

// ---------------- Kernel 4: gather output ------------------------------------
__global__ __launch_bounds__(256) void gather_out(
    const float* __restrict__ selw, const unsigned* __restrict__ selidx,
    const float* __restrict__ tables, float* __restrict__ out) {
  int wid = blockIdx.x * 4 + (threadIdx.x >> 6);
  int lane = threadIdx.x & 63;
  int h = wid >> 11;
  int n = wid & 2047;

  float acc = 0.0f;
#pragma unroll
  for (int t = 0; t < TT; ++t) {
    size_t o = ((size_t)NHT + (size_t)h * TT + t) * NN + n;   // side 1 (k)
    float4 w4 = ((const float4*)selw)[o];
    unsigned ip = selidx[o];
    const float* tb = tables + ((size_t)h * TT + t) * SS * DD;
    acc += w4.x * tb[(ip & 255u) * DD + lane];
    acc += w4.y * tb[((ip >> 8) & 255u) * DD + lane];
    acc += w4.z * tb[((ip >> 16) & 255u) * DD + lane];
    acc += w4.w * tb[(ip >> 24) * DD + lane];
  }
  out[((size_t)h * NN + n) * DD + lane] = acc * 0.125f;
}

extern "C" void kernel_launch(void* const* d_in, const int* in_sizes, int n_in,
                              void* d_out, int out_size, void* d_ws, size_t ws_size,
                              hipStream_t stream) {
  const float* q    = (const float*)d_in[0];
  const float* k    = (const float*)d_in[1];
  const float* v    = (const float*)d_in[2];
  const float* mask = (const float*)d_in[3];
  const float* proj = (const float*)d_in[4];
  float* out = (float*)d_out;

  // ws layout (bytes):
  //   tables  : 96*256*64 f32            = 6,291,456
  //   selw    : 2*96*2048*4 f32          = 6,291,456
  //   selidx  : 2*96*2048 u32            = 1,572,864
  //   counts  : 96*256 u32               =    98,304
  //   offsets : 96*256 u32               =    98,304
  //   entries : 96*8192 u64              = 6,291,456   (total 20,643,840)
  float*    tables = (float*)d_ws;
  float*    selw   = tables + (size_t)NHT * SS * DD;
  unsigned* selidx = (unsigned*)(selw + (size_t)2 * NHT * NN * KK);
  unsigned* counts = selidx + (size_t)2 * NHT * NN;
  unsigned* offsets = counts + (size_t)NHT * SS;
  unsigned long long* entries = (unsigned long long*)(offsets + (size_t)NHT * SS);

  hipMemsetAsync(counts, 0, (size_t)NHT * SS * sizeof(unsigned), stream);

  select_topk<<<dim3(1536), dim3(256), 0, stream>>>(q, k, proj, selw, selidx, counts);
  scan_scatter<<<dim3(NHT), dim3(256), 0, stream>>>(selw, selidx, mask, counts, offsets, entries);
  build_tables<<<dim3(6144), dim3(256), 0, stream>>>(v, counts, offsets, entries, tables);
  gather_out<<<dim3(6144), dim3(256), 0, stream>>>(selw, selidx, tables, out);
}

// Round 6
// 118.388 us; speedup vs baseline: 3.6362x; 1.2315x over previous
//
#include <hip/hip_runtime.h>

// LookupAttention: B=1,H=12,N=2048,D=64, T=8, S=256, C=8, KQ=KV=4
#define HH   12
#define NN   2048
#define DD   64
#define TT   8
#define SS   256
#define KK   4
#define NHT  (HH * TT)   // 96

// ---------------- Kernel 1: selection (both sides) + side-0 bucket counts ----
// Grid: 2 sides * 12 h * 64 tiles = 1536 blocks, 256 threads (4 waves).
// Wave handles 8 rows; lane = (r,t): full per-(n,t) selection serially in-lane.
// Top-4 via exact candidate pruning: flip-cost of bit c is |s_c| (logit
// identity); true top-4 = base XOR {subsets of cheapest bits}. 11 fixed
// candidates (singles+pairs of 4 cheapest), re-evaluated with the bit-exact
// reference product association, ranked by u64 key (exact JAX tie rule).
__global__ __launch_bounds__(256) void select_topk(
    const float* __restrict__ q, const float* __restrict__ kx,
    const float* __restrict__ proj,
    float* __restrict__ selw, unsigned* __restrict__ selidx,
    unsigned* __restrict__ counts) {
  __shared__ float pj[64 * 68];  // row = c*8+t, stride 68 (conflict-free)
  __shared__ float xr[32 * 72];  // row stride 72

  int b = blockIdx.x;
  int side = b / 768;
  int rem  = b - side * 768;
  int h    = rem >> 6;
  int n0   = (rem & 63) * 32;
  const float* src = side ? kx : q;

  for (int e = threadIdx.x; e < 4096; e += 256) {
    int t = e >> 9, c = (e >> 6) & 7, d = e & 63;
    pj[(c * 8 + t) * 68 + d] = proj[h * 4096 + e];
  }
  for (int e = threadIdx.x; e < 2048; e += 256) {
    int r = e >> 6, d = e & 63;
    xr[r * 72 + d] = src[((size_t)h * NN + n0 + r) * DD + d];
  }
  __syncthreads();

  int wave = threadIdx.x >> 6, lane = threadIdx.x & 63;
  int r = lane >> 3, t = lane & 7;
  int row = wave * 8 + r;
  int n = n0 + row;

  // 8 dot products s[c] = x . proj[h][t][c]
  float s[8] = {0.f,0.f,0.f,0.f,0.f,0.f,0.f,0.f};
  const float* xrow = &xr[row * 72];
  for (int d0 = 0; d0 < 64; d0 += 4) {
    float4 xv = *(const float4*)(xrow + d0);
#pragma unroll
    for (int c = 0; c < 8; ++c) {
      float4 pv = *(const float4*)(&pj[(c * 8 + t) * 68 + d0]);
      s[c] += xv.x * pv.x; s[c] += xv.y * pv.y;
      s[c] += xv.z * pv.z; s[c] += xv.w * pv.w;
    }
  }

  float p[8], qn[8];
  float dv[8]; int dc[8];
  int jbase = 0;
#pragma unroll
  for (int c = 0; c < 8; ++c) {
    p[c]  = 1.0f / (1.0f + expf(-s[c]));   // identical expression to verified R3
    qn[c] = 1.0f - p[c];
    dv[c] = fabsf(s[c]); dc[c] = c;
    jbase |= (s[c] > 0.0f) ? (1 << c) : 0; // s>0 -> p>=0.5 -> bit 1 is argmax
  }

  // Batcher odd-even sort, 19 CAS: dv ascending, dc follows (all static idx)
#define CASX(i,j) { bool sw_ = dv[i] > dv[j];                         \
    float tv_ = sw_ ? dv[j] : dv[i]; float uv_ = sw_ ? dv[i] : dv[j]; \
    int   ti_ = sw_ ? dc[j] : dc[i]; int   ui_ = sw_ ? dc[i] : dc[j]; \
    dv[i] = tv_; dv[j] = uv_; dc[i] = ti_; dc[j] = ui_; }
  CASX(0,1) CASX(2,3) CASX(4,5) CASX(6,7)
  CASX(0,2) CASX(1,3) CASX(4,6) CASX(5,7)
  CASX(1,2) CASX(5,6)
  CASX(0,4) CASX(1,5) CASX(2,6) CASX(3,7)
  CASX(2,4) CASX(3,5)
  CASX(1,2) CASX(3,4) CASX(5,6)
#undef CASX

  int M1 = 1 << dc[0], M2 = 1 << dc[1], M3 = 1 << dc[2], M4 = 1 << dc[3];
  int cj[11] = { jbase,
                 jbase ^ M1, jbase ^ M2, jbase ^ M3, jbase ^ M4,
                 jbase ^ (M1|M2), jbase ^ (M1|M3), jbase ^ (M1|M4),
                 jbase ^ (M2|M3), jbase ^ (M2|M4), jbase ^ (M3|M4) };

  unsigned long long K0 = 0, K1 = 0, K2 = 0, K3 = 0;
#pragma unroll
  for (int kc = 0; kc < 11; ++kc) {
    int j = cj[kc];
    // exact final value, reference association: ((f0*f1)*f2)*...*f7
    float w = (j & 1) ? p[0] : qn[0];
#pragma unroll
    for (int c = 1; c < 8; ++c) w *= ((j >> c) & 1) ? p[c] : qn[c];
    // key compare == (value desc, index asc) exactly; w>0 so bits monotone
    unsigned long long key =
        ((unsigned long long)__float_as_uint(w) << 32) | (unsigned)(255 - j);
    bool c0 = key > K0, c1 = key > K1, c2 = key > K2, c3 = key > K3;
    K3 = c2 ? K2 : (c3 ? key : K3);
    K2 = c1 ? K1 : (c2 ? key : K2);
    K1 = c0 ? K0 : (c1 ? key : K1);
    K0 = c0 ? key : K0;
  }

  float m0 = __uint_as_float((unsigned)(K0 >> 32));
  float m1 = __uint_as_float((unsigned)(K1 >> 32));
  float m2 = __uint_as_float((unsigned)(K2 >> 32));
  float m3 = __uint_as_float((unsigned)(K3 >> 32));
  int i0 = 255 - (int)(K0 & 255u);
  int i1 = 255 - (int)(K1 & 255u);
  int i2 = 255 - (int)(K2 & 255u);
  int i3 = 255 - (int)(K3 & 255u);

  int ht = h * TT + t;
  size_t o = ((size_t)side * NHT + ht) * NN + n;
  ((float4*)selw)[o] = make_float4(m0, m1, m2, m3);
  selidx[o] = (unsigned)i0 | ((unsigned)i1 << 8) | ((unsigned)i2 << 16) | ((unsigned)i3 << 24);

  if (side == 0) {  // bucket histogram for the q-side scatter bins
    unsigned* cb = counts + (size_t)ht * SS;
    atomicAdd(&cb[i0], 1u); atomicAdd(&cb[i1], 1u);
    atomicAdd(&cb[i2], 1u); atomicAdd(&cb[i3], 1u);
  }
}

// ---------------- Kernel 2: per-(h,t) scan + scatter entries into bins -------
// Grid: 96 blocks, 1024 threads. Entry = u64 { hi: bits(w*mask), lo: n }.
__global__ __launch_bounds__(1024) void scan_scatter(
    const float* __restrict__ selw, const unsigned* __restrict__ selidx,
    const float* __restrict__ mask, const unsigned* __restrict__ counts,
    unsigned* __restrict__ offsets, unsigned long long* __restrict__ entries) {
  __shared__ unsigned cur[SS];
  int ht = blockIdx.x;
  int tid = threadIdx.x;

  if (tid < 64) {  // wave 0: exclusive scan of 256 counts (4 per lane)
    int lane = tid;
    const unsigned* cb = counts + (size_t)ht * SS;
    unsigned c0 = cb[lane*4], c1 = cb[lane*4+1], c2 = cb[lane*4+2], c3 = cb[lane*4+3];
    unsigned sum = c0 + c1 + c2 + c3;
    unsigned x = sum;
#pragma unroll
    for (int off = 1; off <= 32; off <<= 1) {
      unsigned y = __shfl_up(x, off);
      if (lane >= off) x += y;
    }
    unsigned excl = x - sum;
    unsigned o0 = excl, o1 = excl + c0, o2 = o1 + c1, o3 = o2 + c2;
    cur[lane*4] = o0; cur[lane*4+1] = o1; cur[lane*4+2] = o2; cur[lane*4+3] = o3;
    unsigned* ob = offsets + (size_t)ht * SS;
    ob[lane*4] = o0; ob[lane*4+1] = o1; ob[lane*4+2] = o2; ob[lane*4+3] = o3;
  }
  __syncthreads();

  unsigned long long* eb = entries + (size_t)ht * (NN * KK);
  for (int n = tid; n < NN; n += 1024) {
    size_t o = (size_t)ht * NN + n;   // side 0 region
    float4 w4 = ((const float4*)selw)[o];
    unsigned ip = selidx[o];
    float m = mask[n];
    unsigned b0 = ip & 255u, b1 = (ip >> 8) & 255u, b2 = (ip >> 16) & 255u, b3 = ip >> 24;
    unsigned s0 = atomicAdd(&cur[b0], 1u);
    eb[s0] = ((unsigned long long)__float_as_uint(w4.x * m) << 32) | (unsigned)n;
    unsigned s1 = atomicAdd(&cur[b1], 1u);
    eb[s1] = ((unsigned long long)__float_as_uint(w4.y * m) << 32) | (unsigned)n;
    unsigned s2 = atomicAdd(&cur[b2], 1u);
    eb[s2] = ((unsigned long long)__float_as_uint(w4.z * m) << 32) | (unsigned)n;
    unsigned s3 = atomicAdd(&cur[b3], 1u);
    eb[s3] = ((unsigned long long)__float_as_uint(w4.w * m) << 32) | (unsigned)n;
  }
}

// ---------------- Kernel 3: build tables by gathering bins -------------------
// Grid: 24576 waves / 4 = 6144 blocks. Wave = (ht, s); lane = d. No atomics.
__global__ __launch_bounds__(256) void build_tables(
    const float* __restrict__ v, const unsigned* __restrict__ counts,
    const unsigned* __restrict__ offsets,
    const unsigned long long* __restrict__ entries,
    float* __restrict__ tables) {
  int wid = blockIdx.x * 4 + (threadIdx.x >> 6);
  int lane = threadIdx.x & 63;
  int ht = wid >> 8;
  int s  = wid & 255;
  int h  = ht >> 3;

  unsigned beg = offsets[(size_t)ht * SS + s];
  unsigned cnt = counts [(size_t)ht * SS + s];
  const unsigned long long* e = entries + (size_t)ht * (NN * KK) + beg;
  const float* vh = v + (size_t)h * NN * DD;

  float acc = 0.0f;
  unsigned i = 0;
  for (; i + 2 <= cnt; i += 2) {
    unsigned long long e0 = e[i], e1 = e[i + 1];
    unsigned n0 = (unsigned)e0, n1 = (unsigned)e1;
    float w0 = __uint_as_float((unsigned)(e0 >> 32));
    float w1 = __uint_as_float((unsigned)(e1 >> 32));
    acc += w0 * vh[(size_t)n0 * DD + lane];
    acc += w1 * vh[(size_t)n1 * DD + lane];
  }
  if (i < cnt) {
    unsigned long long e0 = e[i];
    acc += __uint_as_float((unsigned)(e0 >> 32)) * vh[(size_t)(unsigned)e0 * DD + lane];
  }
  tables[(size_t)wid * DD + lane] = acc;
}

// ---------------- Kernel 4: gather output ------------------------------------
__global__ __launch_bounds__(256) void gather_out(
    const float* __restrict__ selw, const unsigned* __restrict__ selidx,
    const float* __restrict__ tables, float* __restrict__ out) {
  int wid = blockIdx.x * 4 + (threadIdx.x >> 6);
  int lane = threadIdx.x & 63;
  int h = wid >> 11;
  int n = wid & 2047;

  float acc = 0.0f;
#pragma unroll
  for (int t = 0; t < TT; ++t) {
    size_t o = ((size_t)NHT + (size_t)h * TT + t) * NN + n;   // side 1 (k)
    float4 w4 = ((const float4*)selw)[o];
    unsigned ip = selidx[o];
    const float* tb = tables + ((size_t)h * TT + t) * SS * DD;
    acc += w4.x * tb[(ip & 255u) * DD + lane];
    acc += w4.y * tb[((ip >> 8) & 255u) * DD + lane];
    acc += w4.z * tb[((ip >> 16) & 255u) * DD + lane];
    acc += w4.w * tb[(ip >> 24) * DD + lane];
  }
  out[((size_t)h * NN + n) * DD + lane] = acc * 0.125f;
}

extern "C" void kernel_launch(void* const* d_in, const int* in_sizes, int n_in,
                              void* d_out, int out_size, void* d_ws, size_t ws_size,
                              hipStream_t stream) {
  const float* q    = (const float*)d_in[0];
  const float* k    = (const float*)d_in[1];
  const float* v    = (const float*)d_in[2];
  const float* mask = (const float*)d_in[3];
  const float* proj = (const float*)d_in[4];
  float* out = (float*)d_out;

  float*    tables = (float*)d_ws;                             // 6.29MB
  float*    selw   = tables + (size_t)NHT * SS * DD;           // 6.29MB
  unsigned* selidx = (unsigned*)(selw + (size_t)2 * NHT * NN * KK);
  unsigned* counts = selidx + (size_t)2 * NHT * NN;
  unsigned* offsets = counts + (size_t)NHT * SS;
  unsigned long long* entries = (unsigned long long*)(offsets + (size_t)NHT * SS);

  hipMemsetAsync(counts, 0, (size_t)NHT * SS * sizeof(unsigned), stream);

  select_topk<<<dim3(1536), dim3(256), 0, stream>>>(q, k, proj, selw, selidx, counts);
  scan_scatter<<<dim3(NHT), dim3(1024), 0, stream>>>(selw, selidx, mask, counts, offsets, entries);
  build_tables<<<dim3(6144), dim3(256), 0, stream>>>(v, counts, offsets, entries, tables);
  gather_out<<<dim3(6144), dim3(256), 0, stream>>>(selw, selidx, tables, out);
}

// Round 7
// 100.481 us; speedup vs baseline: 4.2843x; 1.1782x over previous
//
#include <hip/hip_runtime.h>

// LookupAttention: B=1,H=12,N=2048,D=64, T=8, S=256, C=8, KQ=KV=4
#define HH   12
#define NN   2048
#define DD   64
#define TT   8
#define SS   256
#define KK   4
#define NHT  (HH * TT)   // 96

// XCD-aware block swizzle for 6144-block grids: 8 XCDs x 768 contiguous
// blocks each -> per-XCD L2 keeps ~1.5 h's v/tables resident (m157/m204).
__device__ __forceinline__ int xcd_swz6144(int bid) {
  return (bid & 7) * 768 + (bid >> 3);
}

// ---------------- Kernel 1: selection (both sides) + side-0 bucket counts ----
// Grid: 2 sides * 12 h * 64 tiles = 1536 blocks, 256 threads (4 waves).
// Wave handles 8 rows; lane = (r,t): full per-(n,t) selection serially in-lane.
// Top-4 via exact candidate pruning: flip-cost of bit c is |s_c| (logit
// identity); true top-4 = base XOR {subsets of cheapest bits}. 11 fixed
// candidates (singles+pairs of 4 cheapest), re-evaluated with the bit-exact
// reference product association, ranked by u64 key (exact JAX tie rule).
__global__ __launch_bounds__(256) void select_topk(
    const float* __restrict__ q, const float* __restrict__ kx,
    const float* __restrict__ proj,
    float* __restrict__ selw, unsigned* __restrict__ selidx,
    unsigned* __restrict__ counts) {
  __shared__ float pj[64 * 68];  // row = c*8+t, stride 68 (conflict-free)
  __shared__ float xr[32 * 72];  // row stride 72

  int b = blockIdx.x;
  int side = b / 768;
  int rem  = b - side * 768;
  int h    = rem >> 6;
  int n0   = (rem & 63) * 32;
  const float* src = side ? kx : q;

  for (int e = threadIdx.x; e < 4096; e += 256) {
    int t = e >> 9, c = (e >> 6) & 7, d = e & 63;
    pj[(c * 8 + t) * 68 + d] = proj[h * 4096 + e];
  }
  for (int e = threadIdx.x; e < 2048; e += 256) {
    int r = e >> 6, d = e & 63;
    xr[r * 72 + d] = src[((size_t)h * NN + n0 + r) * DD + d];
  }
  __syncthreads();

  int wave = threadIdx.x >> 6, lane = threadIdx.x & 63;
  int r = lane >> 3, t = lane & 7;
  int row = wave * 8 + r;
  int n = n0 + row;

  // 8 dot products s[c] = x . proj[h][t][c]
  float s[8] = {0.f,0.f,0.f,0.f,0.f,0.f,0.f,0.f};
  const float* xrow = &xr[row * 72];
  for (int d0 = 0; d0 < 64; d0 += 4) {
    float4 xv = *(const float4*)(xrow + d0);
#pragma unroll
    for (int c = 0; c < 8; ++c) {
      float4 pv = *(const float4*)(&pj[(c * 8 + t) * 68 + d0]);
      s[c] += xv.x * pv.x; s[c] += xv.y * pv.y;
      s[c] += xv.z * pv.z; s[c] += xv.w * pv.w;
    }
  }

  float p[8], qn[8];
  float dv[8]; int dc[8];
  int jbase = 0;
#pragma unroll
  for (int c = 0; c < 8; ++c) {
    p[c]  = 1.0f / (1.0f + expf(-s[c]));   // identical expression to verified R3
    qn[c] = 1.0f - p[c];
    dv[c] = fabsf(s[c]); dc[c] = c;
    jbase |= (s[c] > 0.0f) ? (1 << c) : 0; // s>0 -> p>=0.5 -> bit 1 is argmax
  }

  // Batcher odd-even sort, 19 CAS: dv ascending, dc follows (all static idx)
#define CASX(i,j) { bool sw_ = dv[i] > dv[j];                         \
    float tv_ = sw_ ? dv[j] : dv[i]; float uv_ = sw_ ? dv[i] : dv[j]; \
    int   ti_ = sw_ ? dc[j] : dc[i]; int   ui_ = sw_ ? dc[i] : dc[j]; \
    dv[i] = tv_; dv[j] = uv_; dc[i] = ti_; dc[j] = ui_; }
  CASX(0,1) CASX(2,3) CASX(4,5) CASX(6,7)
  CASX(0,2) CASX(1,3) CASX(4,6) CASX(5,7)
  CASX(1,2) CASX(5,6)
  CASX(0,4) CASX(1,5) CASX(2,6) CASX(3,7)
  CASX(2,4) CASX(3,5)
  CASX(1,2) CASX(3,4) CASX(5,6)
#undef CASX

  int M1 = 1 << dc[0], M2 = 1 << dc[1], M3 = 1 << dc[2], M4 = 1 << dc[3];
  int cj[11] = { jbase,
                 jbase ^ M1, jbase ^ M2, jbase ^ M3, jbase ^ M4,
                 jbase ^ (M1|M2), jbase ^ (M1|M3), jbase ^ (M1|M4),
                 jbase ^ (M2|M3), jbase ^ (M2|M4), jbase ^ (M3|M4) };

  unsigned long long K0 = 0, K1 = 0, K2 = 0, K3 = 0;
#pragma unroll
  for (int kc = 0; kc < 11; ++kc) {
    int j = cj[kc];
    // exact final value, reference association: ((f0*f1)*f2)*...*f7
    float w = (j & 1) ? p[0] : qn[0];
#pragma unroll
    for (int c = 1; c < 8; ++c) w *= ((j >> c) & 1) ? p[c] : qn[c];
    // key compare == (value desc, index asc) exactly; w>0 so bits monotone
    unsigned long long key =
        ((unsigned long long)__float_as_uint(w) << 32) | (unsigned)(255 - j);
    bool c0 = key > K0, c1 = key > K1, c2 = key > K2, c3 = key > K3;
    K3 = c2 ? K2 : (c3 ? key : K3);
    K2 = c1 ? K1 : (c2 ? key : K2);
    K1 = c0 ? K0 : (c1 ? key : K1);
    K0 = c0 ? key : K0;
  }

  float m0 = __uint_as_float((unsigned)(K0 >> 32));
  float m1 = __uint_as_float((unsigned)(K1 >> 32));
  float m2 = __uint_as_float((unsigned)(K2 >> 32));
  float m3 = __uint_as_float((unsigned)(K3 >> 32));
  int i0 = 255 - (int)(K0 & 255u);
  int i1 = 255 - (int)(K1 & 255u);
  int i2 = 255 - (int)(K2 & 255u);
  int i3 = 255 - (int)(K3 & 255u);

  int ht = h * TT + t;
  size_t o = ((size_t)side * NHT + ht) * NN + n;
  ((float4*)selw)[o] = make_float4(m0, m1, m2, m3);
  selidx[o] = (unsigned)i0 | ((unsigned)i1 << 8) | ((unsigned)i2 << 16) | ((unsigned)i3 << 24);

  if (side == 0) {  // bucket histogram for the q-side scatter bins
    unsigned* cb = counts + (size_t)ht * SS;
    atomicAdd(&cb[i0], 1u); atomicAdd(&cb[i1], 1u);
    atomicAdd(&cb[i2], 1u); atomicAdd(&cb[i3], 1u);
  }
}

// ---------------- Kernel 2: per-(h,t) scan + scatter entries into bins -------
// Grid: 96 blocks, 1024 threads. Entry = u64 { hi: bits(w*mask), lo: n }.
__global__ __launch_bounds__(1024) void scan_scatter(
    const float* __restrict__ selw, const unsigned* __restrict__ selidx,
    const float* __restrict__ mask, const unsigned* __restrict__ counts,
    unsigned* __restrict__ offsets, unsigned long long* __restrict__ entries) {
  __shared__ unsigned cur[SS];
  int ht = blockIdx.x;
  int tid = threadIdx.x;

  if (tid < 64) {  // wave 0: exclusive scan of 256 counts (4 per lane)
    int lane = tid;
    const unsigned* cb = counts + (size_t)ht * SS;
    unsigned c0 = cb[lane*4], c1 = cb[lane*4+1], c2 = cb[lane*4+2], c3 = cb[lane*4+3];
    unsigned sum = c0 + c1 + c2 + c3;
    unsigned x = sum;
#pragma unroll
    for (int off = 1; off <= 32; off <<= 1) {
      unsigned y = __shfl_up(x, off);
      if (lane >= off) x += y;
    }
    unsigned excl = x - sum;
    unsigned o0 = excl, o1 = excl + c0, o2 = o1 + c1, o3 = o2 + c2;
    cur[lane*4] = o0; cur[lane*4+1] = o1; cur[lane*4+2] = o2; cur[lane*4+3] = o3;
    unsigned* ob = offsets + (size_t)ht * SS;
    ob[lane*4] = o0; ob[lane*4+1] = o1; ob[lane*4+2] = o2; ob[lane*4+3] = o3;
  }
  __syncthreads();

  unsigned long long* eb = entries + (size_t)ht * (NN * KK);
  for (int n = tid; n < NN; n += 1024) {
    size_t o = (size_t)ht * NN + n;   // side 0 region
    float4 w4 = ((const float4*)selw)[o];
    unsigned ip = selidx[o];
    float m = mask[n];
    unsigned b0 = ip & 255u, b1 = (ip >> 8) & 255u, b2 = (ip >> 16) & 255u, b3 = ip >> 24;
    unsigned s0 = atomicAdd(&cur[b0], 1u);
    eb[s0] = ((unsigned long long)__float_as_uint(w4.x * m) << 32) | (unsigned)n;
    unsigned s1 = atomicAdd(&cur[b1], 1u);
    eb[s1] = ((unsigned long long)__float_as_uint(w4.y * m) << 32) | (unsigned)n;
    unsigned s2 = atomicAdd(&cur[b2], 1u);
    eb[s2] = ((unsigned long long)__float_as_uint(w4.z * m) << 32) | (unsigned)n;
    unsigned s3 = atomicAdd(&cur[b3], 1u);
    eb[s3] = ((unsigned long long)__float_as_uint(w4.w * m) << 32) | (unsigned)n;
  }
}

// ---------------- Kernel 3: build tables by gathering bins -------------------
// Grid: 6144 blocks (XCD-swizzled). Wave = (ht, s); lane = d. No atomics.
// 8-deep two-phase loads break the entry->v dependent-latency chain.
__global__ __launch_bounds__(256) void build_tables(
    const float* __restrict__ v, const unsigned* __restrict__ counts,
    const unsigned* __restrict__ offsets,
    const unsigned long long* __restrict__ entries,
    float* __restrict__ tables) {
  int wid = xcd_swz6144(blockIdx.x) * 4 + (threadIdx.x >> 6);
  int lane = threadIdx.x & 63;
  int ht = wid >> 8;
  int s  = wid & 255;
  int h  = ht >> 3;

  unsigned beg = offsets[(size_t)ht * SS + s];
  unsigned cnt = counts [(size_t)ht * SS + s];
  const unsigned long long* e = entries + (size_t)ht * (NN * KK) + beg;
  const float* vh = v + (size_t)h * NN * DD;

  float acc = 0.0f;
  unsigned i = 0;
  for (; i + 8 <= cnt; i += 8) {
    unsigned long long E0 = e[i],   E1 = e[i+1], E2 = e[i+2], E3 = e[i+3];
    unsigned long long E4 = e[i+4], E5 = e[i+5], E6 = e[i+6], E7 = e[i+7];
    float f0 = vh[(size_t)(unsigned)E0 * DD + lane];
    float f1 = vh[(size_t)(unsigned)E1 * DD + lane];
    float f2 = vh[(size_t)(unsigned)E2 * DD + lane];
    float f3 = vh[(size_t)(unsigned)E3 * DD + lane];
    float f4 = vh[(size_t)(unsigned)E4 * DD + lane];
    float f5 = vh[(size_t)(unsigned)E5 * DD + lane];
    float f6 = vh[(size_t)(unsigned)E6 * DD + lane];
    float f7 = vh[(size_t)(unsigned)E7 * DD + lane];
    acc = fmaf(__uint_as_float((unsigned)(E0 >> 32)), f0, acc);
    acc = fmaf(__uint_as_float((unsigned)(E1 >> 32)), f1, acc);
    acc = fmaf(__uint_as_float((unsigned)(E2 >> 32)), f2, acc);
    acc = fmaf(__uint_as_float((unsigned)(E3 >> 32)), f3, acc);
    acc = fmaf(__uint_as_float((unsigned)(E4 >> 32)), f4, acc);
    acc = fmaf(__uint_as_float((unsigned)(E5 >> 32)), f5, acc);
    acc = fmaf(__uint_as_float((unsigned)(E6 >> 32)), f6, acc);
    acc = fmaf(__uint_as_float((unsigned)(E7 >> 32)), f7, acc);
  }
  for (; i < cnt; ++i) {
    unsigned long long e0 = e[i];
    acc += __uint_as_float((unsigned)(e0 >> 32)) * vh[(size_t)(unsigned)e0 * DD + lane];
  }
  tables[(size_t)wid * DD + lane] = acc;
}

// ---------------- Kernel 4: gather output ------------------------------------
// Grid: 6144 blocks (XCD-swizzled). Wave per (h,n); lane = d.
__global__ __launch_bounds__(256) void gather_out(
    const float* __restrict__ selw, const unsigned* __restrict__ selidx,
    const float* __restrict__ tables, float* __restrict__ out) {
  int wid = xcd_swz6144(blockIdx.x) * 4 + (threadIdx.x >> 6);
  int lane = threadIdx.x & 63;
  int h = wid >> 11;
  int n = wid & 2047;

  float acc = 0.0f;
#pragma unroll
  for (int t = 0; t < TT; ++t) {
    size_t o = ((size_t)NHT + (size_t)h * TT + t) * NN + n;   // side 1 (k)
    float4 w4 = ((const float4*)selw)[o];
    unsigned ip = selidx[o];
    const float* tb = tables + ((size_t)h * TT + t) * SS * DD;
    acc += w4.x * tb[(ip & 255u) * DD + lane];
    acc += w4.y * tb[((ip >> 8) & 255u) * DD + lane];
    acc += w4.z * tb[((ip >> 16) & 255u) * DD + lane];
    acc += w4.w * tb[(ip >> 24) * DD + lane];
  }
  out[((size_t)h * NN + n) * DD + lane] = acc * 0.125f;
}

extern "C" void kernel_launch(void* const* d_in, const int* in_sizes, int n_in,
                              void* d_out, int out_size, void* d_ws, size_t ws_size,
                              hipStream_t stream) {
  const float* q    = (const float*)d_in[0];
  const float* k    = (const float*)d_in[1];
  const float* v    = (const float*)d_in[2];
  const float* mask = (const float*)d_in[3];
  const float* proj = (const float*)d_in[4];
  float* out = (float*)d_out;

  float*    tables = (float*)d_ws;                             // 6.29MB
  float*    selw   = tables + (size_t)NHT * SS * DD;           // 6.29MB
  unsigned* selidx = (unsigned*)(selw + (size_t)2 * NHT * NN * KK);
  unsigned* counts = selidx + (size_t)2 * NHT * NN;
  unsigned* offsets = counts + (size_t)NHT * SS;
  unsigned long long* entries = (unsigned long long*)(offsets + (size_t)NHT * SS);

  hipMemsetAsync(counts, 0, (size_t)NHT * SS * sizeof(unsigned), stream);

  select_topk<<<dim3(1536), dim3(256), 0, stream>>>(q, k, proj, selw, selidx, counts);
  scan_scatter<<<dim3(NHT), dim3(1024), 0, stream>>>(selw, selidx, mask, counts, offsets, entries);
  build_tables<<<dim3(6144), dim3(256), 0, stream>>>(v, counts, offsets, entries, tables);
  gather_out<<<dim3(6144), dim3(256), 0, stream>>>(selw, selidx, tables, out);
}

// Round 10
// 92.878 us; speedup vs baseline: 4.6350x; 1.0819x over previous
//
#include <hip/hip_runtime.h>

// LookupAttention: B=1,H=12,N=2048,D=64, T=8, S=256, C=8, KQ=KV=4
#define HH   12
#define NN   2048
#define DD   64
#define TT   8
#define SS   256
#define KK   4
#define NHT  (HH * TT)   // 96

// XCD-aware block swizzle for 6144-block grids: 8 XCDs x 768 contiguous
// blocks each -> per-XCD L2 keeps ~1.5 h's v/tables resident (m157/m204).
__device__ __forceinline__ int xcd_swz6144(int bid) {
  return (bid & 7) * 768 + (bid >> 3);
}

// ---------------- Kernel 1: selection (both sides) + side-0 bucket counts ----
// Grid: 2 sides * 12 h * 64 tiles = 1536 blocks, 256 threads (4 waves).
// Wave handles 8 rows; lane = (t,r): t = lane>>3, r = lane&7 so that the
// 8 lanes of a t-group write 8 CONSECUTIVE n -> 128B contiguous float4
// stores (R7 fix: t=lane&7 gave 64 partial-line stores/wave, 3.8x write amp).
// Top-4 via exact candidate pruning: flip-cost of bit c is |s_c| (logit
// identity); true top-4 = base XOR {subsets of cheapest bits}. 11 fixed
// candidates, re-evaluated with the bit-exact reference product association,
// ranked by u64 key (exact JAX tie rule).
__global__ __launch_bounds__(256) void select_topk(
    const float* __restrict__ q, const float* __restrict__ kx,
    const float* __restrict__ proj,
    float* __restrict__ selw, unsigned* __restrict__ selidx,
    unsigned* __restrict__ counts) {
  __shared__ float pj[64 * 68];  // row = c*8+t, stride 68 (conflict-free)
  __shared__ float xr[32 * 72];  // row stride 72

  int b = blockIdx.x;
  int side = b / 768;
  int rem  = b - side * 768;
  int h    = rem >> 6;
  int n0   = (rem & 63) * 32;
  const float* src = side ? kx : q;

  // stage proj[h] (4096 floats = 1024 float4), rows (c*8+t)
  for (int e4 = threadIdx.x; e4 < 1024; e4 += 256) {
    int e = e4 * 4;
    int t = e >> 9, c = (e >> 6) & 7, d4 = (e >> 2) & 15;
    float4 pv = ((const float4*)(proj + h * 4096))[e4];
    *(float4*)(&pj[(c * 8 + t) * 68 + d4 * 4]) = pv;
  }
  // stage 32 x-rows (2048 floats = 512 float4)
  for (int e4 = threadIdx.x; e4 < 512; e4 += 256) {
    int r = e4 >> 4, d4 = e4 & 15;
    float4 xv = ((const float4*)(src + ((size_t)h * NN + n0 + r) * DD))[d4];
    *(float4*)(&xr[r * 72 + d4 * 4]) = xv;
  }
  __syncthreads();

  int wave = threadIdx.x >> 6, lane = threadIdx.x & 63;
  int t = lane >> 3, r = lane & 7;
  int row = wave * 8 + r;
  int n = n0 + row;

  // 8 dot products s[c] = x . proj[h][t][c]
  float s[8] = {0.f,0.f,0.f,0.f,0.f,0.f,0.f,0.f};
  const float* xrow = &xr[row * 72];
  for (int d0 = 0; d0 < 64; d0 += 4) {
    float4 xv = *(const float4*)(xrow + d0);
#pragma unroll
    for (int c = 0; c < 8; ++c) {
      float4 pv = *(const float4*)(&pj[(c * 8 + t) * 68 + d0]);
      s[c] += xv.x * pv.x; s[c] += xv.y * pv.y;
      s[c] += xv.z * pv.z; s[c] += xv.w * pv.w;
    }
  }

  float p[8], qn[8];
  float dv[8]; int dc[8];
  int jbase = 0;
#pragma unroll
  for (int c = 0; c < 8; ++c) {
    p[c]  = 1.0f / (1.0f + expf(-s[c]));   // identical expression to verified R3
    qn[c] = 1.0f - p[c];
    dv[c] = fabsf(s[c]); dc[c] = c;
    jbase |= (s[c] > 0.0f) ? (1 << c) : 0; // s>0 -> p>=0.5 -> bit 1 is argmax
  }

  // Batcher odd-even sort, 19 CAS: dv ascending, dc follows (all static idx)
#define CASX(i,j) { bool sw_ = dv[i] > dv[j];                         \
    float tv_ = sw_ ? dv[j] : dv[i]; float uv_ = sw_ ? dv[i] : dv[j]; \
    int   ti_ = sw_ ? dc[j] : dc[i]; int   ui_ = sw_ ? dc[i] : dc[j]; \
    dv[i] = tv_; dv[j] = uv_; dc[i] = ti_; dc[j] = ui_; }
  CASX(0,1) CASX(2,3) CASX(4,5) CASX(6,7)
  CASX(0,2) CASX(1,3) CASX(4,6) CASX(5,7)
  CASX(1,2) CASX(5,6)
  CASX(0,4) CASX(1,5) CASX(2,6) CASX(3,7)
  CASX(2,4) CASX(3,5)
  CASX(1,2) CASX(3,4) CASX(5,6)
#undef CASX

  int M1 = 1 << dc[0], M2 = 1 << dc[1], M3 = 1 << dc[2], M4 = 1 << dc[3];
  int cj[11] = { jbase,
                 jbase ^ M1, jbase ^ M2, jbase ^ M3, jbase ^ M4,
                 jbase ^ (M1|M2), jbase ^ (M1|M3), jbase ^ (M1|M4),
                 jbase ^ (M2|M3), jbase ^ (M2|M4), jbase ^ (M3|M4) };

  unsigned long long K0 = 0, K1 = 0, K2 = 0, K3 = 0;
#pragma unroll
  for (int kc = 0; kc < 11; ++kc) {
    int j = cj[kc];
    // exact final value, reference association: ((f0*f1)*f2)*...*f7
    float w = (j & 1) ? p[0] : qn[0];
#pragma unroll
    for (int c = 1; c < 8; ++c) w *= ((j >> c) & 1) ? p[c] : qn[c];
    // key compare == (value desc, index asc) exactly; w>0 so bits monotone
    unsigned long long key =
        ((unsigned long long)__float_as_uint(w) << 32) | (unsigned)(255 - j);
    bool c0 = key > K0, c1 = key > K1, c2 = key > K2, c3 = key > K3;
    K3 = c2 ? K2 : (c3 ? key : K3);
    K2 = c1 ? K1 : (c2 ? key : K2);
    K1 = c0 ? K0 : (c1 ? key : K1);
    K0 = c0 ? key : K0;
  }

  float m0 = __uint_as_float((unsigned)(K0 >> 32));
  float m1 = __uint_as_float((unsigned)(K1 >> 32));
  float m2 = __uint_as_float((unsigned)(K2 >> 32));
  float m3 = __uint_as_float((unsigned)(K3 >> 32));
  int i0 = 255 - (int)(K0 & 255u);
  int i1 = 255 - (int)(K1 & 255u);
  int i2 = 255 - (int)(K2 & 255u);
  int i3 = 255 - (int)(K3 & 255u);

  int ht = h * TT + t;
  size_t o = ((size_t)side * NHT + ht) * NN + n;
  ((float4*)selw)[o] = make_float4(m0, m1, m2, m3);
  selidx[o] = (unsigned)i0 | ((unsigned)i1 << 8) | ((unsigned)i2 << 16) | ((unsigned)i3 << 24);

  if (side == 0) {  // bucket histogram for the q-side scatter bins
    unsigned* cb = counts + (size_t)ht * SS;
    atomicAdd(&cb[i0], 1u); atomicAdd(&cb[i1], 1u);
    atomicAdd(&cb[i2], 1u); atomicAdd(&cb[i3], 1u);
  }
}

// ---------------- Kernel 2: per-(h,t) scan + scatter entries into bins -------
// Grid: 96 blocks, 1024 threads. Entry = u64 { hi: bits(w*mask), lo: n }.
__global__ __launch_bounds__(1024) void scan_scatter(
    const float* __restrict__ selw, const unsigned* __restrict__ selidx,
    const float* __restrict__ mask, const unsigned* __restrict__ counts,
    unsigned* __restrict__ offsets, unsigned long long* __restrict__ entries) {
  __shared__ unsigned cur[SS];
  int ht = blockIdx.x;
  int tid = threadIdx.x;

  if (tid < 64) {  // wave 0: exclusive scan of 256 counts (4 per lane)
    int lane = tid;
    const unsigned* cb = counts + (size_t)ht * SS;
    unsigned c0 = cb[lane*4], c1 = cb[lane*4+1], c2 = cb[lane*4+2], c3 = cb[lane*4+3];
    unsigned sum = c0 + c1 + c2 + c3;
    unsigned x = sum;
#pragma unroll
    for (int off = 1; off <= 32; off <<= 1) {
      unsigned y = __shfl_up(x, off);
      if (lane >= off) x += y;
    }
    unsigned excl = x - sum;
    unsigned o0 = excl, o1 = excl + c0, o2 = o1 + c1, o3 = o2 + c2;
    cur[lane*4] = o0; cur[lane*4+1] = o1; cur[lane*4+2] = o2; cur[lane*4+3] = o3;
    unsigned* ob = offsets + (size_t)ht * SS;
    ob[lane*4] = o0; ob[lane*4+1] = o1; ob[lane*4+2] = o2; ob[lane*4+3] = o3;
  }
  __syncthreads();

  unsigned long long* eb = entries + (size_t)ht * (NN * KK);
  for (int n = tid; n < NN; n += 1024) {
    size_t o = (size_t)ht * NN + n;   // side 0 region
    float4 w4 = ((const float4*)selw)[o];
    unsigned ip = selidx[o];
    float m = mask[n];
    unsigned b0 = ip & 255u, b1 = (ip >> 8) & 255u, b2 = (ip >> 16) & 255u, b3 = ip >> 24;
    unsigned s0 = atomicAdd(&cur[b0], 1u);
    eb[s0] = ((unsigned long long)__float_as_uint(w4.x * m) << 32) | (unsigned)n;
    unsigned s1 = atomicAdd(&cur[b1], 1u);
    eb[s1] = ((unsigned long long)__float_as_uint(w4.y * m) << 32) | (unsigned)n;
    unsigned s2 = atomicAdd(&cur[b2], 1u);
    eb[s2] = ((unsigned long long)__float_as_uint(w4.z * m) << 32) | (unsigned)n;
    unsigned s3 = atomicAdd(&cur[b3], 1u);
    eb[s3] = ((unsigned long long)__float_as_uint(w4.w * m) << 32) | (unsigned)n;
  }
}

// ---------------- Kernel 3: build tables by gathering bins -------------------
// Grid: 6144 blocks (XCD-swizzled). Wave = (ht, s); lane = d. No atomics.
// 8-deep two-phase loads break the entry->v dependent-latency chain.
__global__ __launch_bounds__(256) void build_tables(
    const float* __restrict__ v, const unsigned* __restrict__ counts,
    const unsigned* __restrict__ offsets,
    const unsigned long long* __restrict__ entries,
    float* __restrict__ tables) {
  int wid = xcd_swz6144(blockIdx.x) * 4 + (threadIdx.x >> 6);
  int lane = threadIdx.x & 63;
  int ht = wid >> 8;
  int s  = wid & 255;
  int h  = ht >> 3;

  unsigned beg = offsets[(size_t)ht * SS + s];
  unsigned cnt = counts [(size_t)ht * SS + s];
  const unsigned long long* e = entries + (size_t)ht * (NN * KK) + beg;
  const float* vh = v + (size_t)h * NN * DD;

  float acc = 0.0f;
  unsigned i = 0;
  for (; i + 8 <= cnt; i += 8) {
    unsigned long long E0 = e[i],   E1 = e[i+1], E2 = e[i+2], E3 = e[i+3];
    unsigned long long E4 = e[i+4], E5 = e[i+5], E6 = e[i+6], E7 = e[i+7];
    float f0 = vh[(size_t)(unsigned)E0 * DD + lane];
    float f1 = vh[(size_t)(unsigned)E1 * DD + lane];
    float f2 = vh[(size_t)(unsigned)E2 * DD + lane];
    float f3 = vh[(size_t)(unsigned)E3 * DD + lane];
    float f4 = vh[(size_t)(unsigned)E4 * DD + lane];
    float f5 = vh[(size_t)(unsigned)E5 * DD + lane];
    float f6 = vh[(size_t)(unsigned)E6 * DD + lane];
    float f7 = vh[(size_t)(unsigned)E7 * DD + lane];
    acc = fmaf(__uint_as_float((unsigned)(E0 >> 32)), f0, acc);
    acc = fmaf(__uint_as_float((unsigned)(E1 >> 32)), f1, acc);
    acc = fmaf(__uint_as_float((unsigned)(E2 >> 32)), f2, acc);
    acc = fmaf(__uint_as_float((unsigned)(E3 >> 32)), f3, acc);
    acc = fmaf(__uint_as_float((unsigned)(E4 >> 32)), f4, acc);
    acc = fmaf(__uint_as_float((unsigned)(E5 >> 32)), f5, acc);
    acc = fmaf(__uint_as_float((unsigned)(E6 >> 32)), f6, acc);
    acc = fmaf(__uint_as_float((unsigned)(E7 >> 32)), f7, acc);
  }
  for (; i < cnt; ++i) {
    unsigned long long e0 = e[i];
    acc += __uint_as_float((unsigned)(e0 >> 32)) * vh[(size_t)(unsigned)e0 * DD + lane];
  }
  tables[(size_t)wid * DD + lane] = acc;
}

// ---------------- Kernel 4: gather output ------------------------------------
// Grid: 6144 blocks (XCD-swizzled). Wave per (h,n); lane = d.
__global__ __launch_bounds__(256) void gather_out(
    const float* __restrict__ selw, const unsigned* __restrict__ selidx,
    const float* __restrict__ tables, float* __restrict__ out) {
  int wid = xcd_swz6144(blockIdx.x) * 4 + (threadIdx.x >> 6);
  int lane = threadIdx.x & 63;
  int h = wid >> 11;
  int n = wid & 2047;

  float acc = 0.0f;
#pragma unroll
  for (int t = 0; t < TT; ++t) {
    size_t o = ((size_t)NHT + (size_t)h * TT + t) * NN + n;   // side 1 (k)
    float4 w4 = ((const float4*)selw)[o];
    unsigned ip = selidx[o];
    const float* tb = tables + ((size_t)h * TT + t) * SS * DD;
    acc += w4.x * tb[(ip & 255u) * DD + lane];
    acc += w4.y * tb[((ip >> 8) & 255u) * DD + lane];
    acc += w4.z * tb[((ip >> 16) & 255u) * DD + lane];
    acc += w4.w * tb[(ip >> 24) * DD + lane];
  }
  out[((size_t)h * NN + n) * DD + lane] = acc * 0.125f;
}

extern "C" void kernel_launch(void* const* d_in, const int* in_sizes, int n_in,
                              void* d_out, int out_size, void* d_ws, size_t ws_size,
                              hipStream_t stream) {
  const float* q    = (const float*)d_in[0];
  const float* k    = (const float*)d_in[1];
  const float* v    = (const float*)d_in[2];
  const float* mask = (const float*)d_in[3];
  const float* proj = (const float*)d_in[4];
  float* out = (float*)d_out;

  float*    tables = (float*)d_ws;                             // 6.29MB
  float*    selw   = tables + (size_t)NHT * SS * DD;           // 6.29MB
  unsigned* selidx = (unsigned*)(selw + (size_t)2 * NHT * NN * KK);
  unsigned* counts = selidx + (size_t)2 * NHT * NN;
  unsigned* offsets = counts + (size_t)NHT * SS;
  unsigned long long* entries = (unsigned long long*)(offsets + (size_t)NHT * SS);

  hipMemsetAsync(counts, 0, (size_t)NHT * SS * sizeof(unsigned), stream);

  select_topk<<<dim3(1536), dim3(256), 0, stream>>>(q, k, proj, selw, selidx, counts);
  scan_scatter<<<dim3(NHT), dim3(1024), 0, stream>>>(selw, selidx, mask, counts, offsets, entries);
  build_tables<<<dim3(6144), dim3(256), 0, stream>>>(v, counts, offsets, entries, tables);
  gather_out<<<dim3(6144), dim3(256), 0, stream>>>(selw, selidx, tables, out);
}

// Round 11
// 75.651 us; speedup vs baseline: 5.6905x; 1.2277x over previous
//
#include <hip/hip_runtime.h>

// LookupAttention: B=1,H=12,N=2048,D=64, T=8, S=256, C=8, KQ=KV=4
#define HH   12
#define NN   2048
#define DD   64
#define TT   8
#define SS   256
#define KK   4
#define NHT  (HH * TT)   // 96

// XCD-aware block swizzle for 6144-block grids: 8 XCDs x 768 contiguous
// blocks each -> per-XCD L2 keeps ~1.5 h's v/tables resident (m157/m204).
__device__ __forceinline__ int xcd_swz6144(int bid) {
  return (bid & 7) * 768 + (bid >> 3);
}

// ---------------- Kernel 1: selection (both sides) ---------------------------
// Grid: 2 sides * 12 h * 64 tiles = 1536 blocks, 256 threads (4 waves).
// Wave handles 8 rows; lane = (t,r): t = lane>>3, r = lane&7 -> each 8-lane
// t-group writes 8 consecutive n = 128B contiguous float4 stores.
// Top-4 via exact candidate pruning: flip-cost of bit c is |s_c| (logit
// identity); true top-4 = base XOR {subsets of cheapest bits}. 11 fixed
// candidates, re-evaluated with the bit-exact reference product association,
// ranked by u64 key (exact JAX tie rule).
// R11: histogram atomics removed — scan_scatter builds its own LDS histogram.
__global__ __launch_bounds__(256) void select_topk(
    const float* __restrict__ q, const float* __restrict__ kx,
    const float* __restrict__ proj,
    float* __restrict__ selw, unsigned* __restrict__ selidx) {
  __shared__ float pj[64 * 68];  // row = c*8+t, stride 68 (conflict-free)
  __shared__ float xr[32 * 72];  // row stride 72

  int b = blockIdx.x;
  int side = b / 768;
  int rem  = b - side * 768;
  int h    = rem >> 6;
  int n0   = (rem & 63) * 32;
  const float* src = side ? kx : q;

  // stage proj[h] (4096 floats = 1024 float4), rows (c*8+t)
  for (int e4 = threadIdx.x; e4 < 1024; e4 += 256) {
    int e = e4 * 4;
    int t = e >> 9, c = (e >> 6) & 7, d4 = (e >> 2) & 15;
    float4 pv = ((const float4*)(proj + h * 4096))[e4];
    *(float4*)(&pj[(c * 8 + t) * 68 + d4 * 4]) = pv;
  }
  // stage 32 x-rows (2048 floats = 512 float4)
  for (int e4 = threadIdx.x; e4 < 512; e4 += 256) {
    int r = e4 >> 4, d4 = e4 & 15;
    float4 xv = ((const float4*)(src + ((size_t)h * NN + n0 + r) * DD))[d4];
    *(float4*)(&xr[r * 72 + d4 * 4]) = xv;
  }
  __syncthreads();

  int wave = threadIdx.x >> 6, lane = threadIdx.x & 63;
  int t = lane >> 3, r = lane & 7;
  int row = wave * 8 + r;
  int n = n0 + row;

  // 8 dot products s[c] = x . proj[h][t][c]
  float s[8] = {0.f,0.f,0.f,0.f,0.f,0.f,0.f,0.f};
  const float* xrow = &xr[row * 72];
  for (int d0 = 0; d0 < 64; d0 += 4) {
    float4 xv = *(const float4*)(xrow + d0);
#pragma unroll
    for (int c = 0; c < 8; ++c) {
      float4 pv = *(const float4*)(&pj[(c * 8 + t) * 68 + d0]);
      s[c] += xv.x * pv.x; s[c] += xv.y * pv.y;
      s[c] += xv.z * pv.z; s[c] += xv.w * pv.w;
    }
  }

  float p[8], qn[8];
  float dv[8]; int dc[8];
  int jbase = 0;
#pragma unroll
  for (int c = 0; c < 8; ++c) {
    p[c]  = 1.0f / (1.0f + expf(-s[c]));   // identical expression to verified R3
    qn[c] = 1.0f - p[c];
    dv[c] = fabsf(s[c]); dc[c] = c;
    jbase |= (s[c] > 0.0f) ? (1 << c) : 0; // s>0 -> p>=0.5 -> bit 1 is argmax
  }

  // Batcher odd-even sort, 19 CAS: dv ascending, dc follows (all static idx)
#define CASX(i,j) { bool sw_ = dv[i] > dv[j];                         \
    float tv_ = sw_ ? dv[j] : dv[i]; float uv_ = sw_ ? dv[i] : dv[j]; \
    int   ti_ = sw_ ? dc[j] : dc[i]; int   ui_ = sw_ ? dc[i] : dc[j]; \
    dv[i] = tv_; dv[j] = uv_; dc[i] = ti_; dc[j] = ui_; }
  CASX(0,1) CASX(2,3) CASX(4,5) CASX(6,7)
  CASX(0,2) CASX(1,3) CASX(4,6) CASX(5,7)
  CASX(1,2) CASX(5,6)
  CASX(0,4) CASX(1,5) CASX(2,6) CASX(3,7)
  CASX(2,4) CASX(3,5)
  CASX(1,2) CASX(3,4) CASX(5,6)
#undef CASX

  int M1 = 1 << dc[0], M2 = 1 << dc[1], M3 = 1 << dc[2], M4 = 1 << dc[3];
  int cj[11] = { jbase,
                 jbase ^ M1, jbase ^ M2, jbase ^ M3, jbase ^ M4,
                 jbase ^ (M1|M2), jbase ^ (M1|M3), jbase ^ (M1|M4),
                 jbase ^ (M2|M3), jbase ^ (M2|M4), jbase ^ (M3|M4) };

  unsigned long long K0 = 0, K1 = 0, K2 = 0, K3 = 0;
#pragma unroll
  for (int kc = 0; kc < 11; ++kc) {
    int j = cj[kc];
    // exact final value, reference association: ((f0*f1)*f2)*...*f7
    float w = (j & 1) ? p[0] : qn[0];
#pragma unroll
    for (int c = 1; c < 8; ++c) w *= ((j >> c) & 1) ? p[c] : qn[c];
    // key compare == (value desc, index asc) exactly; w>0 so bits monotone
    unsigned long long key =
        ((unsigned long long)__float_as_uint(w) << 32) | (unsigned)(255 - j);
    bool c0 = key > K0, c1 = key > K1, c2 = key > K2, c3 = key > K3;
    K3 = c2 ? K2 : (c3 ? key : K3);
    K2 = c1 ? K1 : (c2 ? key : K2);
    K1 = c0 ? K0 : (c1 ? key : K1);
    K0 = c0 ? key : K0;
  }

  float m0 = __uint_as_float((unsigned)(K0 >> 32));
  float m1 = __uint_as_float((unsigned)(K1 >> 32));
  float m2 = __uint_as_float((unsigned)(K2 >> 32));
  float m3 = __uint_as_float((unsigned)(K3 >> 32));
  int i0 = 255 - (int)(K0 & 255u);
  int i1 = 255 - (int)(K1 & 255u);
  int i2 = 255 - (int)(K2 & 255u);
  int i3 = 255 - (int)(K3 & 255u);

  int ht = h * TT + t;
  size_t o = ((size_t)side * NHT + ht) * NN + n;
  ((float4*)selw)[o] = make_float4(m0, m1, m2, m3);
  selidx[o] = (unsigned)i0 | ((unsigned)i1 << 8) | ((unsigned)i2 << 16) | ((unsigned)i3 << 24);
}

// ---------------- Kernel 2: histogram + scan + scatter into bins -------------
// Grid: 96 blocks, 1024 threads. Self-contained per (h,t): builds the LDS
// histogram from selidx (identical counts to the old global-atomic version),
// scans, then scatters. Entry = u64 { hi: bits(w*mask), lo: n }.
// Eliminates the counts array AND the 42us graph-captured hipMemsetAsync fill.
__global__ __launch_bounds__(1024) void scan_scatter(
    const float* __restrict__ selw, const unsigned* __restrict__ selidx,
    const float* __restrict__ mask,
    unsigned* __restrict__ offsets, unsigned long long* __restrict__ entries) {
  __shared__ unsigned cur[SS];
  int ht = blockIdx.x;
  int tid = threadIdx.x;

  if (tid < SS) cur[tid] = 0;
  __syncthreads();

  // LDS histogram of the 8192 bucket refs for this ht
  for (int n = tid; n < NN; n += 1024) {
    unsigned ip = selidx[(size_t)ht * NN + n];
    atomicAdd(&cur[ip & 255u], 1u);
    atomicAdd(&cur[(ip >> 8) & 255u], 1u);
    atomicAdd(&cur[(ip >> 16) & 255u], 1u);
    atomicAdd(&cur[ip >> 24], 1u);
  }
  __syncthreads();

  if (tid < 64) {  // wave 0: exclusive scan of 256 counts (4 per lane)
    int lane = tid;
    unsigned c0 = cur[lane*4], c1 = cur[lane*4+1], c2 = cur[lane*4+2], c3 = cur[lane*4+3];
    unsigned sum = c0 + c1 + c2 + c3;
    unsigned x = sum;
#pragma unroll
    for (int off = 1; off <= 32; off <<= 1) {
      unsigned y = __shfl_up(x, off);
      if (lane >= off) x += y;
    }
    unsigned excl = x - sum;
    unsigned o0 = excl, o1 = excl + c0, o2 = o1 + c1, o3 = o2 + c2;
    cur[lane*4] = o0; cur[lane*4+1] = o1; cur[lane*4+2] = o2; cur[lane*4+3] = o3;
    unsigned* ob = offsets + (size_t)ht * SS;
    ob[lane*4] = o0; ob[lane*4+1] = o1; ob[lane*4+2] = o2; ob[lane*4+3] = o3;
  }
  __syncthreads();

  unsigned long long* eb = entries + (size_t)ht * (NN * KK);
  for (int n = tid; n < NN; n += 1024) {
    size_t o = (size_t)ht * NN + n;   // side 0 region
    float4 w4 = ((const float4*)selw)[o];
    unsigned ip = selidx[o];
    float m = mask[n];
    unsigned b0 = ip & 255u, b1 = (ip >> 8) & 255u, b2 = (ip >> 16) & 255u, b3 = ip >> 24;
    unsigned s0 = atomicAdd(&cur[b0], 1u);
    eb[s0] = ((unsigned long long)__float_as_uint(w4.x * m) << 32) | (unsigned)n;
    unsigned s1 = atomicAdd(&cur[b1], 1u);
    eb[s1] = ((unsigned long long)__float_as_uint(w4.y * m) << 32) | (unsigned)n;
    unsigned s2 = atomicAdd(&cur[b2], 1u);
    eb[s2] = ((unsigned long long)__float_as_uint(w4.z * m) << 32) | (unsigned)n;
    unsigned s3 = atomicAdd(&cur[b3], 1u);
    eb[s3] = ((unsigned long long)__float_as_uint(w4.w * m) << 32) | (unsigned)n;
  }
}

// ---------------- Kernel 3: build tables by gathering bins -------------------
// Grid: 6144 blocks (XCD-swizzled). Wave = (ht, s); lane = d. No atomics.
// cnt derived from offsets (per-ht total is always NN*KK = 8192).
// 8-deep two-phase loads break the entry->v dependent-latency chain.
__global__ __launch_bounds__(256) void build_tables(
    const float* __restrict__ v,
    const unsigned* __restrict__ offsets,
    const unsigned long long* __restrict__ entries,
    float* __restrict__ tables) {
  int wid = xcd_swz6144(blockIdx.x) * 4 + (threadIdx.x >> 6);
  int lane = threadIdx.x & 63;
  int ht = wid >> 8;
  int s  = wid & 255;
  int h  = ht >> 3;

  unsigned beg = offsets[(size_t)ht * SS + s];
  unsigned end = (s == SS - 1) ? (NN * KK) : offsets[(size_t)ht * SS + s + 1];
  unsigned cnt = end - beg;
  const unsigned long long* e = entries + (size_t)ht * (NN * KK) + beg;
  const float* vh = v + (size_t)h * NN * DD;

  float acc = 0.0f;
  unsigned i = 0;
  for (; i + 8 <= cnt; i += 8) {
    unsigned long long E0 = e[i],   E1 = e[i+1], E2 = e[i+2], E3 = e[i+3];
    unsigned long long E4 = e[i+4], E5 = e[i+5], E6 = e[i+6], E7 = e[i+7];
    float f0 = vh[(size_t)(unsigned)E0 * DD + lane];
    float f1 = vh[(size_t)(unsigned)E1 * DD + lane];
    float f2 = vh[(size_t)(unsigned)E2 * DD + lane];
    float f3 = vh[(size_t)(unsigned)E3 * DD + lane];
    float f4 = vh[(size_t)(unsigned)E4 * DD + lane];
    float f5 = vh[(size_t)(unsigned)E5 * DD + lane];
    float f6 = vh[(size_t)(unsigned)E6 * DD + lane];
    float f7 = vh[(size_t)(unsigned)E7 * DD + lane];
    acc = fmaf(__uint_as_float((unsigned)(E0 >> 32)), f0, acc);
    acc = fmaf(__uint_as_float((unsigned)(E1 >> 32)), f1, acc);
    acc = fmaf(__uint_as_float((unsigned)(E2 >> 32)), f2, acc);
    acc = fmaf(__uint_as_float((unsigned)(E3 >> 32)), f3, acc);
    acc = fmaf(__uint_as_float((unsigned)(E4 >> 32)), f4, acc);
    acc = fmaf(__uint_as_float((unsigned)(E5 >> 32)), f5, acc);
    acc = fmaf(__uint_as_float((unsigned)(E6 >> 32)), f6, acc);
    acc = fmaf(__uint_as_float((unsigned)(E7 >> 32)), f7, acc);
  }
  for (; i < cnt; ++i) {
    unsigned long long e0 = e[i];
    acc += __uint_as_float((unsigned)(e0 >> 32)) * vh[(size_t)(unsigned)e0 * DD + lane];
  }
  tables[(size_t)wid * DD + lane] = acc;
}

// ---------------- Kernel 4: gather output ------------------------------------
// Grid: 6144 blocks (XCD-swizzled). Wave per (h,n); lane = d.
__global__ __launch_bounds__(256) void gather_out(
    const float* __restrict__ selw, const unsigned* __restrict__ selidx,
    const float* __restrict__ tables, float* __restrict__ out) {
  int wid = xcd_swz6144(blockIdx.x) * 4 + (threadIdx.x >> 6);
  int lane = threadIdx.x & 63;
  int h = wid >> 11;
  int n = wid & 2047;

  float acc = 0.0f;
#pragma unroll
  for (int t = 0; t < TT; ++t) {
    size_t o = ((size_t)NHT + (size_t)h * TT + t) * NN + n;   // side 1 (k)
    float4 w4 = ((const float4*)selw)[o];
    unsigned ip = selidx[o];
    const float* tb = tables + ((size_t)h * TT + t) * SS * DD;
    acc += w4.x * tb[(ip & 255u) * DD + lane];
    acc += w4.y * tb[((ip >> 8) & 255u) * DD + lane];
    acc += w4.z * tb[((ip >> 16) & 255u) * DD + lane];
    acc += w4.w * tb[(ip >> 24) * DD + lane];
  }
  out[((size_t)h * NN + n) * DD + lane] = acc * 0.125f;
}

extern "C" void kernel_launch(void* const* d_in, const int* in_sizes, int n_in,
                              void* d_out, int out_size, void* d_ws, size_t ws_size,
                              hipStream_t stream) {
  const float* q    = (const float*)d_in[0];
  const float* k    = (const float*)d_in[1];
  const float* v    = (const float*)d_in[2];
  const float* mask = (const float*)d_in[3];
  const float* proj = (const float*)d_in[4];
  float* out = (float*)d_out;

  // ws layout: tables 6.29MB | selw 6.29MB | selidx 1.57MB | offsets 96KB |
  //            entries 6.29MB   (total ~20.5MB; no memset needed — every
  //            element of every buffer is overwritten each call)
  float*    tables = (float*)d_ws;
  float*    selw   = tables + (size_t)NHT * SS * DD;
  unsigned* selidx = (unsigned*)(selw + (size_t)2 * NHT * NN * KK);
  unsigned* offsets = selidx + (size_t)2 * NHT * NN;
  unsigned long long* entries = (unsigned long long*)(offsets + (size_t)NHT * SS);

  select_topk<<<dim3(1536), dim3(256), 0, stream>>>(q, k, proj, selw, selidx);
  scan_scatter<<<dim3(NHT), dim3(1024), 0, stream>>>(selw, selidx, mask, offsets, entries);
  build_tables<<<dim3(6144), dim3(256), 0, stream>>>(v, offsets, entries, tables);
  gather_out<<<dim3(6144), dim3(256), 0, stream>>>(selw, selidx, tables, out);
}

// Round 12
// 72.245 us; speedup vs baseline: 5.9587x; 1.0471x over previous
//
#include <hip/hip_runtime.h>

// LookupAttention: B=1,H=12,N=2048,D=64, T=8, S=256, C=8, KQ=KV=4
#define HH   12
#define NN   2048
#define DD   64
#define TT   8
#define SS   256
#define KK   4
#define NHT  (HH * TT)   // 96

// XCD-aware block swizzle for 6144-block grids: 8 XCDs x 768 contiguous
// blocks each -> per-XCD L2 keeps ~1.5 h's v/tables resident (m157/m204).
__device__ __forceinline__ int xcd_swz6144(int bid) {
  return (bid & 7) * 768 + (bid >> 3);
}

// ---------------- Kernel 1: selection (both sides) ---------------------------
// Grid: 2 sides * 12 h * 64 tiles = 1536 blocks, 256 threads (4 waves).
// Wave handles 8 rows; lane = (t,r): t = lane>>3, r = lane&7 -> each 8-lane
// t-group writes 8 consecutive n = 128B contiguous float4 stores.
// Top-4 via exact candidate pruning: flip-cost of bit c is |s_c| (logit
// identity); true top-4 = base XOR {subsets of cheapest bits}. 11 fixed
// candidates, re-evaluated with the bit-exact reference product association,
// ranked by u64 key (exact JAX tie rule).
__global__ __launch_bounds__(256) void select_topk(
    const float* __restrict__ q, const float* __restrict__ kx,
    const float* __restrict__ proj,
    float* __restrict__ selw, unsigned* __restrict__ selidx) {
  __shared__ float pj[64 * 68];  // row = c*8+t, stride 68 (conflict-free)
  __shared__ float xr[32 * 72];  // row stride 72

  int b = blockIdx.x;
  int side = b / 768;
  int rem  = b - side * 768;
  int h    = rem >> 6;
  int n0   = (rem & 63) * 32;
  const float* src = side ? kx : q;

  // stage proj[h] (4096 floats = 1024 float4), rows (c*8+t)
  for (int e4 = threadIdx.x; e4 < 1024; e4 += 256) {
    int e = e4 * 4;
    int t = e >> 9, c = (e >> 6) & 7, d4 = (e >> 2) & 15;
    float4 pv = ((const float4*)(proj + h * 4096))[e4];
    *(float4*)(&pj[(c * 8 + t) * 68 + d4 * 4]) = pv;
  }
  // stage 32 x-rows (2048 floats = 512 float4)
  for (int e4 = threadIdx.x; e4 < 512; e4 += 256) {
    int r = e4 >> 4, d4 = e4 & 15;
    float4 xv = ((const float4*)(src + ((size_t)h * NN + n0 + r) * DD))[d4];
    *(float4*)(&xr[r * 72 + d4 * 4]) = xv;
  }
  __syncthreads();

  int wave = threadIdx.x >> 6, lane = threadIdx.x & 63;
  int t = lane >> 3, r = lane & 7;
  int row = wave * 8 + r;
  int n = n0 + row;

  // 8 dot products s[c] = x . proj[h][t][c]
  float s[8] = {0.f,0.f,0.f,0.f,0.f,0.f,0.f,0.f};
  const float* xrow = &xr[row * 72];
  for (int d0 = 0; d0 < 64; d0 += 4) {
    float4 xv = *(const float4*)(xrow + d0);
#pragma unroll
    for (int c = 0; c < 8; ++c) {
      float4 pv = *(const float4*)(&pj[(c * 8 + t) * 68 + d0]);
      s[c] += xv.x * pv.x; s[c] += xv.y * pv.y;
      s[c] += xv.z * pv.z; s[c] += xv.w * pv.w;
    }
  }

  float p[8], qn[8];
  float dv[8]; int dc[8];
  int jbase = 0;
#pragma unroll
  for (int c = 0; c < 8; ++c) {
    p[c]  = 1.0f / (1.0f + expf(-s[c]));   // identical expression to verified R3
    qn[c] = 1.0f - p[c];
    dv[c] = fabsf(s[c]); dc[c] = c;
    jbase |= (s[c] > 0.0f) ? (1 << c) : 0; // s>0 -> p>=0.5 -> bit 1 is argmax
  }

  // Batcher odd-even sort, 19 CAS: dv ascending, dc follows (all static idx)
#define CASX(i,j) { bool sw_ = dv[i] > dv[j];                         \
    float tv_ = sw_ ? dv[j] : dv[i]; float uv_ = sw_ ? dv[i] : dv[j]; \
    int   ti_ = sw_ ? dc[j] : dc[i]; int   ui_ = sw_ ? dc[i] : dc[j]; \
    dv[i] = tv_; dv[j] = uv_; dc[i] = ti_; dc[j] = ui_; }
  CASX(0,1) CASX(2,3) CASX(4,5) CASX(6,7)
  CASX(0,2) CASX(1,3) CASX(4,6) CASX(5,7)
  CASX(1,2) CASX(5,6)
  CASX(0,4) CASX(1,5) CASX(2,6) CASX(3,7)
  CASX(2,4) CASX(3,5)
  CASX(1,2) CASX(3,4) CASX(5,6)
#undef CASX

  int M1 = 1 << dc[0], M2 = 1 << dc[1], M3 = 1 << dc[2], M4 = 1 << dc[3];
  int cj[11] = { jbase,
                 jbase ^ M1, jbase ^ M2, jbase ^ M3, jbase ^ M4,
                 jbase ^ (M1|M2), jbase ^ (M1|M3), jbase ^ (M1|M4),
                 jbase ^ (M2|M3), jbase ^ (M2|M4), jbase ^ (M3|M4) };

  unsigned long long K0 = 0, K1 = 0, K2 = 0, K3 = 0;
#pragma unroll
  for (int kc = 0; kc < 11; ++kc) {
    int j = cj[kc];
    // exact final value, reference association: ((f0*f1)*f2)*...*f7
    float w = (j & 1) ? p[0] : qn[0];
#pragma unroll
    for (int c = 1; c < 8; ++c) w *= ((j >> c) & 1) ? p[c] : qn[c];
    // key compare == (value desc, index asc) exactly; w>0 so bits monotone
    unsigned long long key =
        ((unsigned long long)__float_as_uint(w) << 32) | (unsigned)(255 - j);
    bool c0 = key > K0, c1 = key > K1, c2 = key > K2, c3 = key > K3;
    K3 = c2 ? K2 : (c3 ? key : K3);
    K2 = c1 ? K1 : (c2 ? key : K2);
    K1 = c0 ? K0 : (c1 ? key : K1);
    K0 = c0 ? key : K0;
  }

  float m0 = __uint_as_float((unsigned)(K0 >> 32));
  float m1 = __uint_as_float((unsigned)(K1 >> 32));
  float m2 = __uint_as_float((unsigned)(K2 >> 32));
  float m3 = __uint_as_float((unsigned)(K3 >> 32));
  int i0 = 255 - (int)(K0 & 255u);
  int i1 = 255 - (int)(K1 & 255u);
  int i2 = 255 - (int)(K2 & 255u);
  int i3 = 255 - (int)(K3 & 255u);

  int ht = h * TT + t;
  size_t o = ((size_t)side * NHT + ht) * NN + n;
  ((float4*)selw)[o] = make_float4(m0, m1, m2, m3);
  selidx[o] = (unsigned)i0 | ((unsigned)i1 << 8) | ((unsigned)i2 << 16) | ((unsigned)i3 << 24);
}

// ---------------- Kernel 2: histogram + scan + scatter into bins -------------
// Grid: 96 blocks, 1024 threads. Self-contained per (h,t): LDS histogram ->
// wave-0 scan -> scatter into LDS ebuf (64KB, random 8B LDS writes ~free) ->
// one fully-coalesced 64KB dump to global (R12: was scattered global u64
// stores, ~8x write amplification). Entry = u64 { hi: bits(w*mask), lo: n }.
__global__ __launch_bounds__(1024) void scan_scatter(
    const float* __restrict__ selw, const unsigned* __restrict__ selidx,
    const float* __restrict__ mask,
    unsigned* __restrict__ offsets, unsigned long long* __restrict__ entries) {
  __shared__ unsigned long long ebuf[NN * KK];  // 64 KB
  __shared__ unsigned cur[SS];
  int ht = blockIdx.x;
  int tid = threadIdx.x;

  if (tid < SS) cur[tid] = 0;
  __syncthreads();

  // LDS histogram of the 8192 bucket refs for this ht
  for (int n = tid; n < NN; n += 1024) {
    unsigned ip = selidx[(size_t)ht * NN + n];
    atomicAdd(&cur[ip & 255u], 1u);
    atomicAdd(&cur[(ip >> 8) & 255u], 1u);
    atomicAdd(&cur[(ip >> 16) & 255u], 1u);
    atomicAdd(&cur[ip >> 24], 1u);
  }
  __syncthreads();

  if (tid < 64) {  // wave 0: exclusive scan of 256 counts (4 per lane)
    int lane = tid;
    unsigned c0 = cur[lane*4], c1 = cur[lane*4+1], c2 = cur[lane*4+2], c3 = cur[lane*4+3];
    unsigned sum = c0 + c1 + c2 + c3;
    unsigned x = sum;
#pragma unroll
    for (int off = 1; off <= 32; off <<= 1) {
      unsigned y = __shfl_up(x, off);
      if (lane >= off) x += y;
    }
    unsigned excl = x - sum;
    unsigned o0 = excl, o1 = excl + c0, o2 = o1 + c1, o3 = o2 + c2;
    cur[lane*4] = o0; cur[lane*4+1] = o1; cur[lane*4+2] = o2; cur[lane*4+3] = o3;
    unsigned* ob = offsets + (size_t)ht * SS;
    ob[lane*4] = o0; ob[lane*4+1] = o1; ob[lane*4+2] = o2; ob[lane*4+3] = o3;
  }
  __syncthreads();

  // scatter into LDS ebuf
  for (int n = tid; n < NN; n += 1024) {
    size_t o = (size_t)ht * NN + n;   // side 0 region
    float4 w4 = ((const float4*)selw)[o];
    unsigned ip = selidx[o];
    float m = mask[n];
    unsigned b0 = ip & 255u, b1 = (ip >> 8) & 255u, b2 = (ip >> 16) & 255u, b3 = ip >> 24;
    unsigned s0 = atomicAdd(&cur[b0], 1u);
    ebuf[s0] = ((unsigned long long)__float_as_uint(w4.x * m) << 32) | (unsigned)n;
    unsigned s1 = atomicAdd(&cur[b1], 1u);
    ebuf[s1] = ((unsigned long long)__float_as_uint(w4.y * m) << 32) | (unsigned)n;
    unsigned s2 = atomicAdd(&cur[b2], 1u);
    ebuf[s2] = ((unsigned long long)__float_as_uint(w4.z * m) << 32) | (unsigned)n;
    unsigned s3 = atomicAdd(&cur[b3], 1u);
    ebuf[s3] = ((unsigned long long)__float_as_uint(w4.w * m) << 32) | (unsigned)n;
  }
  __syncthreads();

  // coalesced dump: 8192 u64 = 64KB contiguous
  unsigned long long* eb = entries + (size_t)ht * (NN * KK);
  for (int i = tid; i < NN * KK; i += 1024) eb[i] = ebuf[i];
}

// ---------------- Kernel 3: build tables by gathering bins -------------------
// Grid: 6144 blocks (XCD-swizzled). Wave = (ht, s); lane = d. No atomics.
// cnt derived from offsets (per-ht total is always NN*KK = 8192).
// 8-deep two-phase loads break the entry->v dependent-latency chain.
__global__ __launch_bounds__(256) void build_tables(
    const float* __restrict__ v,
    const unsigned* __restrict__ offsets,
    const unsigned long long* __restrict__ entries,
    float* __restrict__ tables) {
  int wid = xcd_swz6144(blockIdx.x) * 4 + (threadIdx.x >> 6);
  int lane = threadIdx.x & 63;
  int ht = wid >> 8;
  int s  = wid & 255;
  int h  = ht >> 3;

  unsigned beg = offsets[(size_t)ht * SS + s];
  unsigned end = (s == SS - 1) ? (NN * KK) : offsets[(size_t)ht * SS + s + 1];
  unsigned cnt = end - beg;
  const unsigned long long* e = entries + (size_t)ht * (NN * KK) + beg;
  const float* vh = v + (size_t)h * NN * DD;

  float acc = 0.0f;
  unsigned i = 0;
  for (; i + 8 <= cnt; i += 8) {
    unsigned long long E0 = e[i],   E1 = e[i+1], E2 = e[i+2], E3 = e[i+3];
    unsigned long long E4 = e[i+4], E5 = e[i+5], E6 = e[i+6], E7 = e[i+7];
    float f0 = vh[(size_t)(unsigned)E0 * DD + lane];
    float f1 = vh[(size_t)(unsigned)E1 * DD + lane];
    float f2 = vh[(size_t)(unsigned)E2 * DD + lane];
    float f3 = vh[(size_t)(unsigned)E3 * DD + lane];
    float f4 = vh[(size_t)(unsigned)E4 * DD + lane];
    float f5 = vh[(size_t)(unsigned)E5 * DD + lane];
    float f6 = vh[(size_t)(unsigned)E6 * DD + lane];
    float f7 = vh[(size_t)(unsigned)E7 * DD + lane];
    acc = fmaf(__uint_as_float((unsigned)(E0 >> 32)), f0, acc);
    acc = fmaf(__uint_as_float((unsigned)(E1 >> 32)), f1, acc);
    acc = fmaf(__uint_as_float((unsigned)(E2 >> 32)), f2, acc);
    acc = fmaf(__uint_as_float((unsigned)(E3 >> 32)), f3, acc);
    acc = fmaf(__uint_as_float((unsigned)(E4 >> 32)), f4, acc);
    acc = fmaf(__uint_as_float((unsigned)(E5 >> 32)), f5, acc);
    acc = fmaf(__uint_as_float((unsigned)(E6 >> 32)), f6, acc);
    acc = fmaf(__uint_as_float((unsigned)(E7 >> 32)), f7, acc);
  }
  for (; i < cnt; ++i) {
    unsigned long long e0 = e[i];
    acc += __uint_as_float((unsigned)(e0 >> 32)) * vh[(size_t)(unsigned)e0 * DD + lane];
  }
  tables[(size_t)wid * DD + lane] = acc;
}

// ---------------- Kernel 4: gather output ------------------------------------
// Grid: 6144 blocks (XCD-swizzled). Wave per (h,n); lane = d.
__global__ __launch_bounds__(256) void gather_out(
    const float* __restrict__ selw, const unsigned* __restrict__ selidx,
    const float* __restrict__ tables, float* __restrict__ out) {
  int wid = xcd_swz6144(blockIdx.x) * 4 + (threadIdx.x >> 6);
  int lane = threadIdx.x & 63;
  int h = wid >> 11;
  int n = wid & 2047;

  float acc = 0.0f;
#pragma unroll
  for (int t = 0; t < TT; ++t) {
    size_t o = ((size_t)NHT + (size_t)h * TT + t) * NN + n;   // side 1 (k)
    float4 w4 = ((const float4*)selw)[o];
    unsigned ip = selidx[o];
    const float* tb = tables + ((size_t)h * TT + t) * SS * DD;
    acc += w4.x * tb[(ip & 255u) * DD + lane];
    acc += w4.y * tb[((ip >> 8) & 255u) * DD + lane];
    acc += w4.z * tb[((ip >> 16) & 255u) * DD + lane];
    acc += w4.w * tb[(ip >> 24) * DD + lane];
  }
  out[((size_t)h * NN + n) * DD + lane] = acc * 0.125f;
}

extern "C" void kernel_launch(void* const* d_in, const int* in_sizes, int n_in,
                              void* d_out, int out_size, void* d_ws, size_t ws_size,
                              hipStream_t stream) {
  const float* q    = (const float*)d_in[0];
  const float* k    = (const float*)d_in[1];
  const float* v    = (const float*)d_in[2];
  const float* mask = (const float*)d_in[3];
  const float* proj = (const float*)d_in[4];
  float* out = (float*)d_out;

  // ws layout: tables 6.29MB | selw 6.29MB | selidx 1.57MB | offsets 96KB |
  //            entries 6.29MB   (total ~20.5MB; no memset needed — every
  //            element of every buffer is overwritten each call)
  float*    tables = (float*)d_ws;
  float*    selw   = tables + (size_t)NHT * SS * DD;
  unsigned* selidx = (unsigned*)(selw + (size_t)2 * NHT * NN * KK);
  unsigned* offsets = selidx + (size_t)2 * NHT * NN;
  unsigned long long* entries = (unsigned long long*)(offsets + (size_t)NHT * SS);

  select_topk<<<dim3(1536), dim3(256), 0, stream>>>(q, k, proj, selw, selidx);
  scan_scatter<<<dim3(NHT), dim3(1024), 0, stream>>>(selw, selidx, mask, offsets, entries);
  build_tables<<<dim3(6144), dim3(256), 0, stream>>>(v, offsets, entries, tables);
  gather_out<<<dim3(6144), dim3(256), 0, stream>>>(selw, selidx, tables, out);
}

// Round 13
// 71.677 us; speedup vs baseline: 6.0060x; 1.0079x over previous
//
#include <hip/hip_runtime.h>

// LookupAttention: B=1,H=12,N=2048,D=64, T=8, S=256, C=8, KQ=KV=4
#define HH   12
#define NN   2048
#define DD   64
#define TT   8
#define SS   256
#define KK   4
#define NHT  (HH * TT)   // 96

// XCD-aware block swizzle for 6144-block grids: 8 XCDs x 768 contiguous
// blocks each -> per-XCD L2 keeps ~1.5 h's v/tables resident (m157/m204).
__device__ __forceinline__ int xcd_swz6144(int bid) {
  return (bid & 7) * 768 + (bid >> 3);
}

// Per-task selection: sigmoid -> |logit| Batcher sort -> 11 candidates ->
// exact u64-key top-4 -> coalesced store. Verified bit-identical to the
// full 256-scan (R3..R12). s[8] are the 8 hash dot products.
__device__ __forceinline__ void select_store(
    const float* __restrict__ s, int side, int ht, int n,
    float* __restrict__ selw, unsigned* __restrict__ selidx) {
  float p[8], qn[8];
  float dv[8]; int dc[8];
  int jbase = 0;
#pragma unroll
  for (int c = 0; c < 8; ++c) {
    p[c]  = 1.0f / (1.0f + expf(-s[c]));   // identical expression to verified R3
    qn[c] = 1.0f - p[c];
    dv[c] = fabsf(s[c]); dc[c] = c;
    jbase |= (s[c] > 0.0f) ? (1 << c) : 0; // s>0 -> p>=0.5 -> bit 1 is argmax
  }

  // Batcher odd-even sort, 19 CAS: dv ascending, dc follows (all static idx)
#define CASX(i,j) { bool sw_ = dv[i] > dv[j];                         \
    float tv_ = sw_ ? dv[j] : dv[i]; float uv_ = sw_ ? dv[i] : dv[j]; \
    int   ti_ = sw_ ? dc[j] : dc[i]; int   ui_ = sw_ ? dc[i] : dc[j]; \
    dv[i] = tv_; dv[j] = uv_; dc[i] = ti_; dc[j] = ui_; }
  CASX(0,1) CASX(2,3) CASX(4,5) CASX(6,7)
  CASX(0,2) CASX(1,3) CASX(4,6) CASX(5,7)
  CASX(1,2) CASX(5,6)
  CASX(0,4) CASX(1,5) CASX(2,6) CASX(3,7)
  CASX(2,4) CASX(3,5)
  CASX(1,2) CASX(3,4) CASX(5,6)
#undef CASX

  int M1 = 1 << dc[0], M2 = 1 << dc[1], M3 = 1 << dc[2], M4 = 1 << dc[3];
  int cj[11] = { jbase,
                 jbase ^ M1, jbase ^ M2, jbase ^ M3, jbase ^ M4,
                 jbase ^ (M1|M2), jbase ^ (M1|M3), jbase ^ (M1|M4),
                 jbase ^ (M2|M3), jbase ^ (M2|M4), jbase ^ (M3|M4) };

  unsigned long long K0 = 0, K1 = 0, K2 = 0, K3 = 0;
#pragma unroll
  for (int kc = 0; kc < 11; ++kc) {
    int j = cj[kc];
    float w = (j & 1) ? p[0] : qn[0];   // reference association ((f0*f1)*..)*f7
#pragma unroll
    for (int c = 1; c < 8; ++c) w *= ((j >> c) & 1) ? p[c] : qn[c];
    unsigned long long key =
        ((unsigned long long)__float_as_uint(w) << 32) | (unsigned)(255 - j);
    bool c0 = key > K0, c1 = key > K1, c2 = key > K2, c3 = key > K3;
    K3 = c2 ? K2 : (c3 ? key : K3);
    K2 = c1 ? K1 : (c2 ? key : K2);
    K1 = c0 ? K0 : (c1 ? key : K1);
    K0 = c0 ? key : K0;
  }

  float m0 = __uint_as_float((unsigned)(K0 >> 32));
  float m1 = __uint_as_float((unsigned)(K1 >> 32));
  float m2 = __uint_as_float((unsigned)(K2 >> 32));
  float m3 = __uint_as_float((unsigned)(K3 >> 32));
  int i0 = 255 - (int)(K0 & 255u);
  int i1 = 255 - (int)(K1 & 255u);
  int i2 = 255 - (int)(K2 & 255u);
  int i3 = 255 - (int)(K3 & 255u);

  size_t o = ((size_t)side * NHT + ht) * NN + n;
  ((float4*)selw)[o] = make_float4(m0, m1, m2, m3);
  selidx[o] = (unsigned)i0 | ((unsigned)i1 << 8) | ((unsigned)i2 << 16) | ((unsigned)i3 << 24);
}

// ---------------- Kernel 1: selection (both sides) ---------------------------
// Grid: 2 sides * 12 h * 32 tiles = 768 blocks, 256 threads (4 waves).
// Block covers 64 rows. Wave covers 16 rows; lane = (t,rg): t = lane>>3,
// rg = lane&7; lane processes TWO rows (rg, rg+8) sharing one pj stream:
// 160 ds_read_b128 per 2 tasks vs 144 per task before (R13: select was
// LDS-instr-throughput-bound, 128 of 144 reads were un-reused pj traffic).
// Stores stay coalesced: two 8-lane contiguous float4 groups per t-group.
__global__ __launch_bounds__(256) void select_topk(
    const float* __restrict__ q, const float* __restrict__ kx,
    const float* __restrict__ proj,
    float* __restrict__ selw, unsigned* __restrict__ selidx) {
  __shared__ float pj[64 * 68];  // row = c*8+t, stride 68 (conflict-free)
  __shared__ float xr[64 * 72];  // row stride 72

  int b = blockIdx.x;
  int side = b / 384;
  int rem  = b - side * 384;
  int h    = rem >> 5;
  int n0   = (rem & 31) * 64;
  const float* src = side ? kx : q;

  // stage proj[h] (4096 floats = 1024 float4), rows (c*8+t)
  for (int e4 = threadIdx.x; e4 < 1024; e4 += 256) {
    int e = e4 * 4;
    int t = e >> 9, c = (e >> 6) & 7, d4 = (e >> 2) & 15;
    float4 pv = ((const float4*)(proj + h * 4096))[e4];
    *(float4*)(&pj[(c * 8 + t) * 68 + d4 * 4]) = pv;
  }
  // stage 64 x-rows (4096 floats = 1024 float4)
  for (int e4 = threadIdx.x; e4 < 1024; e4 += 256) {
    int r = e4 >> 4, d4 = e4 & 15;
    float4 xv = ((const float4*)(src + ((size_t)h * NN + n0 + r) * DD))[d4];
    *(float4*)(&xr[r * 72 + d4 * 4]) = xv;
  }
  __syncthreads();

  int wave = threadIdx.x >> 6, lane = threadIdx.x & 63;
  int t = lane >> 3, rg = lane & 7;
  int rowa = wave * 16 + rg;        // first row for this lane
  int rowb = rowa + 8;              // second row

  // 8+8 dot products, shared pj stream
  float sa[8] = {0.f,0.f,0.f,0.f,0.f,0.f,0.f,0.f};
  float sb[8] = {0.f,0.f,0.f,0.f,0.f,0.f,0.f,0.f};
  const float* xa = &xr[rowa * 72];
  const float* xb = &xr[rowb * 72];
  for (int d0 = 0; d0 < 64; d0 += 4) {
    float4 xva = *(const float4*)(xa + d0);
    float4 xvb = *(const float4*)(xb + d0);
#pragma unroll
    for (int c = 0; c < 8; ++c) {
      float4 pv = *(const float4*)(&pj[(c * 8 + t) * 68 + d0]);
      sa[c] += xva.x * pv.x; sa[c] += xva.y * pv.y;
      sa[c] += xva.z * pv.z; sa[c] += xva.w * pv.w;
      sb[c] += xvb.x * pv.x; sb[c] += xvb.y * pv.y;
      sb[c] += xvb.z * pv.z; sb[c] += xvb.w * pv.w;
    }
  }

  int ht = h * TT + t;
  select_store(sa, side, ht, n0 + rowa, selw, selidx);
  select_store(sb, side, ht, n0 + rowb, selw, selidx);
}

// ---------------- Kernel 2: histogram + scan + scatter into bins -------------
// Grid: 96 blocks, 1024 threads. Self-contained per (h,t): LDS histogram ->
// wave-0 scan -> scatter into LDS ebuf (64KB) -> coalesced 64KB dump.
// Entry = u64 { hi: bits(w*mask), lo: n }.
__global__ __launch_bounds__(1024) void scan_scatter(
    const float* __restrict__ selw, const unsigned* __restrict__ selidx,
    const float* __restrict__ mask,
    unsigned* __restrict__ offsets, unsigned long long* __restrict__ entries) {
  __shared__ unsigned long long ebuf[NN * KK];  // 64 KB
  __shared__ unsigned cur[SS];
  int ht = blockIdx.x;
  int tid = threadIdx.x;

  if (tid < SS) cur[tid] = 0;
  __syncthreads();

  for (int n = tid; n < NN; n += 1024) {
    unsigned ip = selidx[(size_t)ht * NN + n];
    atomicAdd(&cur[ip & 255u], 1u);
    atomicAdd(&cur[(ip >> 8) & 255u], 1u);
    atomicAdd(&cur[(ip >> 16) & 255u], 1u);
    atomicAdd(&cur[ip >> 24], 1u);
  }
  __syncthreads();

  if (tid < 64) {  // wave 0: exclusive scan of 256 counts (4 per lane)
    int lane = tid;
    unsigned c0 = cur[lane*4], c1 = cur[lane*4+1], c2 = cur[lane*4+2], c3 = cur[lane*4+3];
    unsigned sum = c0 + c1 + c2 + c3;
    unsigned x = sum;
#pragma unroll
    for (int off = 1; off <= 32; off <<= 1) {
      unsigned y = __shfl_up(x, off);
      if (lane >= off) x += y;
    }
    unsigned excl = x - sum;
    unsigned o0 = excl, o1 = excl + c0, o2 = o1 + c1, o3 = o2 + c2;
    cur[lane*4] = o0; cur[lane*4+1] = o1; cur[lane*4+2] = o2; cur[lane*4+3] = o3;
    unsigned* ob = offsets + (size_t)ht * SS;
    ob[lane*4] = o0; ob[lane*4+1] = o1; ob[lane*4+2] = o2; ob[lane*4+3] = o3;
  }
  __syncthreads();

  for (int n = tid; n < NN; n += 1024) {
    size_t o = (size_t)ht * NN + n;   // side 0 region
    float4 w4 = ((const float4*)selw)[o];
    unsigned ip = selidx[o];
    float m = mask[n];
    unsigned b0 = ip & 255u, b1 = (ip >> 8) & 255u, b2 = (ip >> 16) & 255u, b3 = ip >> 24;
    unsigned s0 = atomicAdd(&cur[b0], 1u);
    ebuf[s0] = ((unsigned long long)__float_as_uint(w4.x * m) << 32) | (unsigned)n;
    unsigned s1 = atomicAdd(&cur[b1], 1u);
    ebuf[s1] = ((unsigned long long)__float_as_uint(w4.y * m) << 32) | (unsigned)n;
    unsigned s2 = atomicAdd(&cur[b2], 1u);
    ebuf[s2] = ((unsigned long long)__float_as_uint(w4.z * m) << 32) | (unsigned)n;
    unsigned s3 = atomicAdd(&cur[b3], 1u);
    ebuf[s3] = ((unsigned long long)__float_as_uint(w4.w * m) << 32) | (unsigned)n;
  }
  __syncthreads();

  unsigned long long* eb = entries + (size_t)ht * (NN * KK);
  for (int i = tid; i < NN * KK; i += 1024) eb[i] = ebuf[i];
}

// ---------------- Kernel 3: build tables by gathering bins -------------------
// Grid: 6144 blocks (XCD-swizzled). Wave = (ht, s); lane = d. No atomics.
// cnt derived from offsets; 8-deep two-phase loads for ILP.
__global__ __launch_bounds__(256) void build_tables(
    const float* __restrict__ v,
    const unsigned* __restrict__ offsets,
    const unsigned long long* __restrict__ entries,
    float* __restrict__ tables) {
  int wid = xcd_swz6144(blockIdx.x) * 4 + (threadIdx.x >> 6);
  int lane = threadIdx.x & 63;
  int ht = wid >> 8;
  int s  = wid & 255;
  int h  = ht >> 3;

  unsigned beg = offsets[(size_t)ht * SS + s];
  unsigned end = (s == SS - 1) ? (NN * KK) : offsets[(size_t)ht * SS + s + 1];
  unsigned cnt = end - beg;
  const unsigned long long* e = entries + (size_t)ht * (NN * KK) + beg;
  const float* vh = v + (size_t)h * NN * DD;

  float acc = 0.0f;
  unsigned i = 0;
  for (; i + 8 <= cnt; i += 8) {
    unsigned long long E0 = e[i],   E1 = e[i+1], E2 = e[i+2], E3 = e[i+3];
    unsigned long long E4 = e[i+4], E5 = e[i+5], E6 = e[i+6], E7 = e[i+7];
    float f0 = vh[(size_t)(unsigned)E0 * DD + lane];
    float f1 = vh[(size_t)(unsigned)E1 * DD + lane];
    float f2 = vh[(size_t)(unsigned)E2 * DD + lane];
    float f3 = vh[(size_t)(unsigned)E3 * DD + lane];
    float f4 = vh[(size_t)(unsigned)E4 * DD + lane];
    float f5 = vh[(size_t)(unsigned)E5 * DD + lane];
    float f6 = vh[(size_t)(unsigned)E6 * DD + lane];
    float f7 = vh[(size_t)(unsigned)E7 * DD + lane];
    acc = fmaf(__uint_as_float((unsigned)(E0 >> 32)), f0, acc);
    acc = fmaf(__uint_as_float((unsigned)(E1 >> 32)), f1, acc);
    acc = fmaf(__uint_as_float((unsigned)(E2 >> 32)), f2, acc);
    acc = fmaf(__uint_as_float((unsigned)(E3 >> 32)), f3, acc);
    acc = fmaf(__uint_as_float((unsigned)(E4 >> 32)), f4, acc);
    acc = fmaf(__uint_as_float((unsigned)(E5 >> 32)), f5, acc);
    acc = fmaf(__uint_as_float((unsigned)(E6 >> 32)), f6, acc);
    acc = fmaf(__uint_as_float((unsigned)(E7 >> 32)), f7, acc);
  }
  for (; i < cnt; ++i) {
    unsigned long long e0 = e[i];
    acc += __uint_as_float((unsigned)(e0 >> 32)) * vh[(size_t)(unsigned)e0 * DD + lane];
  }
  tables[(size_t)wid * DD + lane] = acc;
}

// ---------------- Kernel 4: gather output ------------------------------------
// Grid: 6144 blocks (XCD-swizzled). Wave per (h,n); lane = d.
// R13: full ILP batch — preload all 8 (w4,ip), issue all 32 table-row loads,
// then fma in the exact original t-then-k order (bit-identical accumulation).
__global__ __launch_bounds__(256) void gather_out(
    const float* __restrict__ selw, const unsigned* __restrict__ selidx,
    const float* __restrict__ tables, float* __restrict__ out) {
  int wid = xcd_swz6144(blockIdx.x) * 4 + (threadIdx.x >> 6);
  int lane = threadIdx.x & 63;
  int h = wid >> 11;
  int n = wid & 2047;

  float4 w4[8]; unsigned ip[8];
#pragma unroll
  for (int t = 0; t < TT; ++t) {
    size_t o = ((size_t)NHT + (size_t)h * TT + t) * NN + n;   // side 1 (k)
    w4[t] = ((const float4*)selw)[o];
    ip[t] = selidx[o];
  }
  float f[32];
#pragma unroll
  for (int t = 0; t < TT; ++t) {
    const float* tb = tables + ((size_t)h * TT + t) * SS * DD;
    f[t*4+0] = tb[(ip[t] & 255u) * DD + lane];
    f[t*4+1] = tb[((ip[t] >> 8) & 255u) * DD + lane];
    f[t*4+2] = tb[((ip[t] >> 16) & 255u) * DD + lane];
    f[t*4+3] = tb[(ip[t] >> 24) * DD + lane];
  }
  float acc = 0.0f;
#pragma unroll
  for (int t = 0; t < TT; ++t) {
    acc += w4[t].x * f[t*4+0];
    acc += w4[t].y * f[t*4+1];
    acc += w4[t].z * f[t*4+2];
    acc += w4[t].w * f[t*4+3];
  }
  out[((size_t)h * NN + n) * DD + lane] = acc * 0.125f;
}

extern "C" void kernel_launch(void* const* d_in, const int* in_sizes, int n_in,
                              void* d_out, int out_size, void* d_ws, size_t ws_size,
                              hipStream_t stream) {
  const float* q    = (const float*)d_in[0];
  const float* k    = (const float*)d_in[1];
  const float* v    = (const float*)d_in[2];
  const float* mask = (const float*)d_in[3];
  const float* proj = (const float*)d_in[4];
  float* out = (float*)d_out;

  // ws layout: tables 6.29MB | selw 6.29MB | selidx 1.57MB | offsets 96KB |
  //            entries 6.29MB (total ~20.5MB; every element overwritten
  //            each call — no memset needed)
  float*    tables = (float*)d_ws;
  float*    selw   = tables + (size_t)NHT * SS * DD;
  unsigned* selidx = (unsigned*)(selw + (size_t)2 * NHT * NN * KK);
  unsigned* offsets = selidx + (size_t)2 * NHT * NN;
  unsigned long long* entries = (unsigned long long*)(offsets + (size_t)NHT * SS);

  select_topk<<<dim3(768), dim3(256), 0, stream>>>(q, k, proj, selw, selidx);
  scan_scatter<<<dim3(NHT), dim3(1024), 0, stream>>>(selw, selidx, mask, offsets, entries);
  build_tables<<<dim3(6144), dim3(256), 0, stream>>>(v, offsets, entries, tables);
  gather_out<<<dim3(6144), dim3(256), 0, stream>>>(selw, selidx, tables, out);
}